// Round 5
// baseline (652.975 us; speedup 1.0000x reference)
//
#include <hip/hip_runtime.h>

// ---------------------------------------------------------------------------
// Fused multimodal net: l-MLP + 2 LSTMs (MFMA bf16, LDS-staged) + tiny
// transformer head. N=4096, T=256, DA=74, DV=47, hidden=32.
//
// LSTM: block = 512 threads = 8 waves, 16 samples, K=32 MFMA.
// Gate-row map: G = (colc&3)*32 + wid*4 + (colc>>2): lane (q,colc) C-regs
// 0..3 = i,f,g,o of unit wid*4+q, sample colc  (one unit per lane).
// Producer/consumer ring: at step t produce gxN = bias + Wih@x[t+1]
// (off-chain MFMAs), consume acc = mfma(Whh, h[t-1], gxC) (single on-chain
// MFMA). Only h ds_read + 1 MFMA + trans + ds_write_b16 sit between barriers.
// x staged via global_load_lds (TS=4 double buffer, waves 0-3), vmcnt(0)
// only at stage boundaries; main loop unrolled by 2 groups => all LDS
// addressing static. h exchanged via ping-pong H buffers, 1 barrier/step.
// ---------------------------------------------------------------------------

typedef float float4v __attribute__((ext_vector_type(4)));
typedef float float2v __attribute__((ext_vector_type(2)));
typedef short short8v __attribute__((ext_vector_type(8)));

#define N_SAMPLES 4096
#define T_STEPS 256
#define TS 4
#define NST (T_STEPS / TS)  // 64
#define HSTR 40             // shorts per sample row in H (32 units + pad)
#define HBUF (16 * HSTR)    // shorts per H buffer

#define LGKM0 asm volatile("s_waitcnt lgkmcnt(0)" ::: "memory")
#define VM0 asm volatile("s_waitcnt vmcnt(0)" ::: "memory")

__device__ __forceinline__ short bf16r(float f) {
  unsigned u = __float_as_uint(f);
  u += 0x7FFFu + ((u >> 16) & 1u);
  return (short)(u >> 16);
}
__device__ __forceinline__ unsigned cvt_pk_bf16(float lo, float hi) {
  unsigned r;
  asm("v_cvt_pk_bf16_f32 %0, %1, %2" : "=v"(r) : "v"(lo), "v"(hi));
  return r;
}
__device__ __forceinline__ float sigmoidf_(float v) {
  return __fdividef(1.0f, 1.0f + __expf(-v));
}
__device__ __forceinline__ float tanhf_fast(float v) {
  return 1.0f - __fdividef(2.0f, __expf(2.0f * v) + 1.0f);
}
__device__ __forceinline__ float4v mfma32(short8v a, short8v b, float4v c) {
  return __builtin_amdgcn_mfma_f32_16x16x32_bf16(a, b, c, 0, 0, 0);
}
__device__ __forceinline__ void gld16(const float* g, float* l) {
  __builtin_amdgcn_global_load_lds(
      (const __attribute__((address_space(1))) unsigned int*)g,
      (__attribute__((address_space(3))) unsigned int*)l, 16, 0, 0);
}

// LDS: xbuf 2*TS*16*74*4 = 37888 + pad 64 + H 2*640*2 = 2560 => 40512
#define SMEM_BYTES (2 * TS * 16 * 74 * 4 + 64 + 2 * HBUF * 2)

template <int D, int NK32>
__device__ void lstm8(const float* __restrict__ x,
                      const float* __restrict__ Wih,
                      const float* __restrict__ Whh,
                      const float* __restrict__ bih,
                      const float* __restrict__ bhh,
                      const float* __restrict__ Wo,
                      const float* __restrict__ bo,
                      float* __restrict__ outf, int n0, char* smem) {
  constexpr int FPS = 16 * D;   // floats per step slot (packed)
  constexpr int UPS = FPS / 4;  // 16B units per step

  float* xb0 = (float*)smem;        // even-group buffer [TS][FPS]
  float* xb1 = xb0 + TS * FPS;      // odd-group buffer
  unsigned short* Hu = (unsigned short*)(smem + 2 * TS * FPS * 4 + 64);

  const int tid = threadIdx.x;
  const int wid = tid >> 6;    // 0..7
  const int lane = tid & 63;
  const int colc = lane & 15;  // sample col / A-row
  const int q = lane >> 4;     // k-octet selector

  // waves 0-3 stage step g*TS+wid into dst (linear LDS dest)
  auto stage = [&](int g, float* dst) {
    if (wid < 4) {
      const int t = g * TS + wid;
      const float* gs = x + (size_t)t * (N_SAMPLES * D) + (size_t)n0 * D;
      float* ls = dst + wid * FPS;
#pragma unroll
      for (int r = 0; r < UPS / 64; ++r)
        gld16(gs + (r * 64 + lane) * 4, ls + r * 64 * 4);
      constexpr int rem = UPS % 64;
      if (rem) {
        if (lane < rem)
          gld16(gs + ((UPS / 64) * 64 + lane) * 4, ls + (UPS / 64) * 64 * 4);
      }
    }
  };

  stage(0, xb0);  // overlap weight/bias loading with first-stage HBM latency

  // tail mask for kt = NK32-1 (zero d >= D); dword j covers elems 2j,2j+1
  unsigned mm[4];
#pragma unroll
  for (int j = 0; j < 4; ++j) {
    const int d0 = (NK32 - 1) * 32 + q * 8 + 2 * j;
    mm[j] = ((d0 < D) ? 0xFFFFu : 0u) | ((d0 + 1 < D) ? 0xFFFF0000u : 0u);
  }

  // stationary weights: ONE 16-row gate tile per wave
  const int G = (colc & 3) * 32 + wid * 4 + (colc >> 2);
  short8v wfx[NK32], wfh;
  float4v binit;
  {
    const float* wr = Wih + G * D;
#pragma unroll
    for (int kt = 0; kt < NK32; ++kt) {
      short8v s;
#pragma unroll
      for (int e = 0; e < 8; ++e) {
        const int d = kt * 32 + q * 8 + e;
        s[e] = (d < D) ? bf16r(wr[d]) : (short)0;
      }
      wfx[kt] = s;
    }
    const float* hr = Whh + G * 32;
#pragma unroll
    for (int e = 0; e < 8; ++e) wfh[e] = bf16r(hr[q * 8 + e]);
#pragma unroll
    for (int r = 0; r < 4; ++r) {
      const int Gr = r * 32 + wid * 4 + q;  // C reg r -> gate r, unit wid*4+q
      binit[r] = bih[Gr] + bhh[Gr];
    }
  }

  // zero both H buffers (640 dwords)
  {
    unsigned* Hz = (unsigned*)Hu;
    for (int i = tid; i < 640; i += 512) Hz[i] = 0;
  }
  VM0;    // stage-0 landed
  LGKM0;  // H zeros visible
  __builtin_amdgcn_s_barrier();

  // read+convert one step's x row into B-fragments
  auto ldcvt = [&](const float* xnext, short8v* xo) {
    const float* xs = xnext + colc * D;
#pragma unroll
    for (int kt = 0; kt < NK32; ++kt) {
      const float* p = xs + kt * 32 + q * 8;
      const float2v r0 = *(const float2v*)(p);
      const float2v r1 = *(const float2v*)(p + 2);
      const float2v r2 = *(const float2v*)(p + 4);
      const float2v r3 = *(const float2v*)(p + 6);
      union { short8v s; unsigned u[4]; } fr;
      fr.u[0] = cvt_pk_bf16(r0[0], r0[1]);
      fr.u[1] = cvt_pk_bf16(r1[0], r1[1]);
      fr.u[2] = cvt_pk_bf16(r2[0], r2[1]);
      fr.u[3] = cvt_pk_bf16(r3[0], r3[1]);
      if (kt == NK32 - 1) {
#pragma unroll
        for (int j = 0; j < 4; ++j) fr.u[j] &= mm[j];
      }
      xo[kt] = fr.s;
    }
  };

  float c0 = 0.0f;
  float4v gxC;  // bias + Wih@x for the CURRENT step (produced last step)
  {
    short8v xF[NK32];
    ldcvt(xb0, xF);  // x[0]
    float4v g4 = binit;
#pragma unroll
    for (int kt = 0; kt < NK32; ++kt) g4 = mfma32(wfx[kt], xF[kt], g4);
    gxC = g4;
  }

  // one recurrence step: consume gxC + h(prev), produce gx for t+1
  auto step = [&](int PB, const float* xnext) {
    // on-chain: h read (b128) issued first
    const short8v hB =
        *(const short8v*)(Hu + PB * HBUF + colc * HSTR + q * 8);
    // off-chain: x[t+1] read+cvt+produce (fills hB latency)
    short8v xN[NK32];
    ldcvt(xnext, xN);
    float4v gxN = binit;
#pragma unroll
    for (int kt = 0; kt < NK32; ++kt) gxN = mfma32(wfx[kt], xN[kt], gxN);
    // on-chain: single dependent MFMA + lane-local trans
    const float4v acc = mfma32(wfh, hB, gxC);
    const float iv = sigmoidf_(acc[0]);
    const float fv = sigmoidf_(acc[1]);
    const float gv = tanhf_fast(acc[2]);
    const float ov = sigmoidf_(acc[3]);
    const float cv = fv * c0 + iv * gv;
    c0 = cv;
    const float hv = ov * tanhf_fast(cv);
    Hu[(1 - PB) * HBUF + colc * HSTR + wid * 4 + q] =
        (unsigned short)bf16r(hv);
    LGKM0;  // h write visible
    __builtin_amdgcn_s_barrier();
    gxC = gxN;
  };

  // main loop: 2 groups (8 steps) per iteration -> all addressing static
  for (int gg = 0; gg < NST; gg += 2) {
    stage(gg + 1, xb1);
    step(0, xb0 + 1 * FPS);
    step(1, xb0 + 2 * FPS);
    step(0, xb0 + 3 * FPS);
    VM0;  // stage(gg+1) landed
    step(1, xb1);
    if (gg + 2 < NST) stage(gg + 2, xb0);
    step(0, xb1 + 1 * FPS);
    step(1, xb1 + 2 * FPS);
    step(0, xb1 + 3 * FPS);
    VM0;  // stage(gg+2) landed (or nothing outstanding on last iter)
    step(1, xb0);  // last iter: produces garbage gxN, never consumed
  }

  // epilogue: h[255] in H buffer 0; out = relu(h @ Wo^T + bo), waves 0,1
  if (wid < 2) {
    const short8v hB = *(const short8v*)(Hu + colc * HSTR + q * 8);
    const float* wor = Wo + (16 * wid + colc) * 32;
    short8v w8;
#pragma unroll
    for (int e = 0; e < 8; ++e) w8[e] = bf16r(wor[q * 8 + e]);
    float4v o4 = {0.0f, 0.0f, 0.0f, 0.0f};
    o4 = mfma32(w8, hB, o4);
    float4v res;
#pragma unroll
    for (int r = 0; r < 4; ++r)
      res[r] = fmaxf(o4[r] + bo[16 * wid + q * 4 + r], 0.0f);
    *(float4v*)(outf + (size_t)(n0 + colc) * 32 + 16 * wid + q * 4) = res;
  }
}

__global__ __launch_bounds__(512, 4) void lstm_both(
    const float* __restrict__ a, const float* __restrict__ v,
    const float* __restrict__ aWih, const float* __restrict__ aWhh,
    const float* __restrict__ abih, const float* __restrict__ abhh,
    const float* __restrict__ aWo, const float* __restrict__ abo,
    const float* __restrict__ vWih, const float* __restrict__ vWhh,
    const float* __restrict__ vbih, const float* __restrict__ vbhh,
    const float* __restrict__ vWo, const float* __restrict__ vbo,
    float* __restrict__ afw, float* __restrict__ vfw) {
  __shared__ __align__(16) char smem[SMEM_BYTES];
  const int b = blockIdx.x;
  if (b < 256)
    lstm8<74, 3>(a, aWih, aWhh, abih, abhh, aWo, abo, afw, b * 16, smem);
  else
    lstm8<47, 2>(v, vWih, vWhh, vbih, vbhh, vWo, vbo, vfw, (b - 256) * 16,
                 smem);
}

// ---------------------------------------------------------------------------
// lf = relu(relu(l @ lW1^T + lb1) @ lW2^T + lb2)   [4096,768]->[4096,32]
// ---------------------------------------------------------------------------
__global__ __launch_bounds__(256) void lf_kernel(
    const float* __restrict__ l, const float* __restrict__ lW1,
    const float* __restrict__ lb1, const float* __restrict__ lW2,
    const float* __restrict__ lb2, float* __restrict__ lf) {
  __shared__ __align__(16) float lsh[16 * 768];
  __shared__ __align__(16) float h1sh[16 * 128];
  const int tid = threadIdx.x;
  const int n0 = blockIdx.x * 16;

  {
    const float4v* src = (const float4v*)(l + (size_t)n0 * 768);
    float4v* dst = (float4v*)lsh;
#pragma unroll
    for (int i = 0; i < 12; ++i) dst[tid + i * 256] = src[tid + i * 256];
  }
  __syncthreads();

  {
    const int u = tid & 127;
    const int sg = tid >> 7;
    float acc[8];
#pragma unroll
    for (int i = 0; i < 8; ++i) acc[i] = 0.0f;
    const float4v* wrow = (const float4v*)(lW1 + u * 768);
    for (int k4 = 0; k4 < 192; ++k4) {
      const float4v w = wrow[k4];
#pragma unroll
      for (int i = 0; i < 8; ++i) {
        const float4v xv = ((const float4v*)(lsh + (sg * 8 + i) * 768))[k4];
        acc[i] += w[0] * xv[0] + w[1] * xv[1] + w[2] * xv[2] + w[3] * xv[3];
      }
    }
    const float b = lb1[u];
#pragma unroll
    for (int i = 0; i < 8; ++i)
      h1sh[(sg * 8 + i) * 128 + u] = fmaxf(acc[i] + b, 0.0f);
  }
  __syncthreads();

  {
    const int u2 = tid & 31;
    const int sg2 = tid >> 5;
    float acc0 = 0.0f, acc1 = 0.0f;
    const float4v* w2 = (const float4v*)(lW2 + u2 * 128);
#pragma unroll
    for (int k4 = 0; k4 < 32; ++k4) {
      const float4v w = w2[k4];
      const float4v xa = ((const float4v*)(h1sh + sg2 * 128))[k4];
      const float4v xb = ((const float4v*)(h1sh + (sg2 + 8) * 128))[k4];
      acc0 += w[0] * xa[0] + w[1] * xa[1] + w[2] * xa[2] + w[3] * xa[3];
      acc1 += w[0] * xb[0] + w[1] * xb[1] + w[2] * xb[2] + w[3] * xb[3];
    }
    const float b2 = lb2[u2];
    lf[(size_t)(n0 + sg2) * 32 + u2] = fmaxf(acc0 + b2, 0.0f);
    lf[(size_t)(n0 + sg2 + 8) * 32 + u2] = fmaxf(acc1 + b2, 0.0f);
  }
}

// ---------------------------------------------------------------------------
// Transformer block + post-fusion head. 32 lanes/sample, 8 samples/block.
// ---------------------------------------------------------------------------
__global__ __launch_bounds__(256) void head_kernel(
    const float* __restrict__ lf, const float* __restrict__ af,
    const float* __restrict__ vf, const float* __restrict__ Wq,
    const float* __restrict__ bq, const float* __restrict__ Wk,
    const float* __restrict__ bk, const float* __restrict__ Wv,
    const float* __restrict__ bv, const float* __restrict__ Wz,
    const float* __restrict__ bz, const float* __restrict__ Wff,
    const float* __restrict__ bff, const float* __restrict__ g1,
    const float* __restrict__ be1, const float* __restrict__ g2,
    const float* __restrict__ be2, const float* __restrict__ Wp1,
    const float* __restrict__ bp1, const float* __restrict__ Wp2,
    const float* __restrict__ bp2, float* __restrict__ out) {
  __shared__ float shA[8][3][33];
  __shared__ float shB[8][3][33];
  const int tid = threadIdx.x;
  const int j = tid & 31;
  const int slot = tid >> 5;
  const int n = blockIdx.x * 8 + slot;
  const size_t off = (size_t)n * 32 + j;

  const float x0 = lf[off], x1 = af[off], x2 = vf[off];

  auto ln3 = [&](float a0, float a1, float a2, const float* g,
                 const float* be, float* o) {
    float s = a0 + a1 + a2;
    s += __shfl_xor(s, 1); s += __shfl_xor(s, 2); s += __shfl_xor(s, 4);
    s += __shfl_xor(s, 8); s += __shfl_xor(s, 16);
    const float mu = s * (1.0f / 96.0f);
    const float d0 = a0 - mu, d1 = a1 - mu, d2 = a2 - mu;
    float ss = d0 * d0 + d1 * d1 + d2 * d2;
    ss += __shfl_xor(ss, 1); ss += __shfl_xor(ss, 2); ss += __shfl_xor(ss, 4);
    ss += __shfl_xor(ss, 8); ss += __shfl_xor(ss, 16);
    const float rs = rsqrtf(ss * (1.0f / 96.0f) + 1e-5f);
    o[0] = d0 * rs * g[j] + be[j];
    o[1] = d1 * rs * g[32 + j] + be[32 + j];
    o[2] = d2 * rs * g[64 + j] + be[64 + j];
  };

  float z[3];
  ln3(x0, x1, x2, g1, be1, z);
  shA[slot][0][j] = z[0]; shA[slot][1][j] = z[1]; shA[slot][2][j] = z[2];
  __syncthreads();

  float qv[3], kv[3], vv[3];
  {
    const float bqj = bq[j], bkj = bk[j], bvj = bv[j];
    qv[0] = bqj; qv[1] = bqj; qv[2] = bqj;
    kv[0] = bkj; kv[1] = bkj; kv[2] = bkj;
    vv[0] = bvj; vv[1] = bvj; vv[2] = bvj;
    const float* wqr = Wq + j * 32;
    const float* wkr = Wk + j * 32;
    const float* wvr = Wv + j * 32;
#pragma unroll 8
    for (int k = 0; k < 32; ++k) {
      const float zz0 = shA[slot][0][k], zz1 = shA[slot][1][k],
                  zz2 = shA[slot][2][k];
      const float wq = wqr[k], wk_ = wkr[k], wv_ = wvr[k];
      qv[0] += wq * zz0;  qv[1] += wq * zz1;  qv[2] += wq * zz2;
      kv[0] += wk_ * zz0; kv[1] += wk_ * zz1; kv[2] += wk_ * zz2;
      vv[0] += wv_ * zz0; vv[1] += wv_ * zz1; vv[2] += wv_ * zz2;
    }
  }

  float at[3][3];
#pragma unroll
  for (int s = 0; s < 3; ++s)
#pragma unroll
    for (int t2 = 0; t2 < 3; ++t2) {
      float p = qv[s] * kv[t2];
      p += __shfl_xor(p, 1); p += __shfl_xor(p, 2); p += __shfl_xor(p, 4);
      at[s][t2] = p;
    }
#pragma unroll
  for (int s = 0; s < 3; ++s) {
    const float m = fmaxf(fmaxf(at[s][0], at[s][1]), at[s][2]);
    const float e0 = __expf(at[s][0] - m), e1 = __expf(at[s][1] - m),
                e2 = __expf(at[s][2] - m);
    const float sc = 0.35355339059327373f * __fdividef(1.0f, e0 + e1 + e2);
    at[s][0] = e0 * sc; at[s][1] = e1 * sc; at[s][2] = e2 * sc;
  }
  float zc[3];
#pragma unroll
  for (int s = 0; s < 3; ++s)
    zc[s] = at[s][0] * vv[0] + at[s][1] * vv[1] + at[s][2] * vv[2];
  shB[slot][0][j] = zc[0]; shB[slot][1][j] = zc[1]; shB[slot][2][j] = zc[2];
  __syncthreads();

  const float bzj = bz[j];
  float z2a[3] = {bzj + x0, bzj + x1, bzj + x2};
  {
    const float* wzr = Wz + j * 32;
#pragma unroll 8
    for (int k = 0; k < 32; ++k) {
      const float w = wzr[k];
      z2a[0] += w * shB[slot][0][k];
      z2a[1] += w * shB[slot][1][k];
      z2a[2] += w * shB[slot][2][k];
    }
  }

  float zn[3];
  ln3(z2a[0], z2a[1], z2a[2], g2, be2, zn);
  shA[slot][0][j] = zn[0]; shA[slot][1][j] = zn[1]; shA[slot][2][j] = zn[2];
  __syncthreads();

  const float bffj = bff[j];
  float Za[3] = {bffj + z2a[0], bffj + z2a[1], bffj + z2a[2]};
  {
    const float* wfr = Wff + j * 32;
#pragma unroll 8
    for (int k = 0; k < 32; ++k) {
      const float w = wfr[k];
      Za[0] += w * shA[slot][0][k];
      Za[1] += w * shA[slot][1][k];
      Za[2] += w * shA[slot][2][k];
    }
  }
  shB[slot][0][j] = Za[0]; shB[slot][1][j] = Za[1]; shB[slot][2][j] = Za[2];
  __syncthreads();

  float p = bp1[j];
  {
    const float* wpr = Wp1 + j * 96;
#pragma unroll
    for (int s = 0; s < 3; ++s)
#pragma unroll 8
      for (int k = 0; k < 32; ++k) p += wpr[s * 32 + k] * shB[slot][s][k];
  }
  p = fmaxf(p, 0.0f);
  float l0 = Wp2[j] * p, l1 = Wp2[32 + j] * p;
  l0 += __shfl_xor(l0, 1); l0 += __shfl_xor(l0, 2); l0 += __shfl_xor(l0, 4);
  l0 += __shfl_xor(l0, 8); l0 += __shfl_xor(l0, 16);
  l1 += __shfl_xor(l1, 1); l1 += __shfl_xor(l1, 2); l1 += __shfl_xor(l1, 4);
  l1 += __shfl_xor(l1, 8); l1 += __shfl_xor(l1, 16);
  l0 += bp2[0]; l1 += bp2[1];
  const float mx = fmaxf(l0, l1);
  const float e0 = __expf(l0 - mx), e1 = __expf(l1 - mx);
  const float inv = __fdividef(1.0f, e0 + e1);
  if (j == 0) {
    out[(size_t)n * 2 + 0] = e0 * inv;
    out[(size_t)n * 2 + 1] = e1 * inv;
  }
}

// ---------------------------------------------------------------------------
extern "C" void kernel_launch(void* const* d_in, const int* in_sizes, int n_in,
                              void* d_out, int out_size, void* d_ws,
                              size_t ws_size, hipStream_t stream) {
  const float* l    = (const float*)d_in[0];
  const float* a    = (const float*)d_in[1];
  const float* v    = (const float*)d_in[2];
  const float* lW1  = (const float*)d_in[3];
  const float* lb1  = (const float*)d_in[4];
  const float* lW2  = (const float*)d_in[5];
  const float* lb2  = (const float*)d_in[6];
  const float* aWih = (const float*)d_in[7];
  const float* aWhh = (const float*)d_in[8];
  const float* abih = (const float*)d_in[9];
  const float* abhh = (const float*)d_in[10];
  const float* aWo  = (const float*)d_in[11];
  const float* abo  = (const float*)d_in[12];
  const float* vWih = (const float*)d_in[13];
  const float* vWhh = (const float*)d_in[14];
  const float* vbih = (const float*)d_in[15];
  const float* vbhh = (const float*)d_in[16];
  const float* vWo  = (const float*)d_in[17];
  const float* vbo  = (const float*)d_in[18];
  const float* Wq   = (const float*)d_in[19];
  const float* bq   = (const float*)d_in[20];
  const float* Wk   = (const float*)d_in[21];
  const float* bk   = (const float*)d_in[22];
  const float* Wv   = (const float*)d_in[23];
  const float* bv   = (const float*)d_in[24];
  const float* Wz   = (const float*)d_in[25];
  const float* bz   = (const float*)d_in[26];
  const float* Wff  = (const float*)d_in[27];
  const float* bff  = (const float*)d_in[28];
  const float* g1   = (const float*)d_in[29];
  const float* be1  = (const float*)d_in[30];
  const float* g2   = (const float*)d_in[31];
  const float* be2  = (const float*)d_in[32];
  const float* Wp1  = (const float*)d_in[33];
  const float* bp1  = (const float*)d_in[34];
  const float* Wp2  = (const float*)d_in[35];
  const float* bp2  = (const float*)d_in[36];

  float* out = (float*)d_out;
  float* ws = (float*)d_ws;
  float* lfw = ws;
  float* afw = ws + 4096 * 32;
  float* vfw = ws + 2 * 4096 * 32;

  hipLaunchKernelGGL(lstm_both, dim3(512), dim3(512), 0, stream, a, v, aWih,
                     aWhh, abih, abhh, aWo, abo, vWih, vWhh, vbih, vbhh, vWo,
                     vbo, afw, vfw);
  hipLaunchKernelGGL(lf_kernel, dim3(256), dim3(256), 0, stream, l, lW1, lb1,
                     lW2, lb2, lfw);
  hipLaunchKernelGGL(head_kernel, dim3(512), dim3(256), 0, stream, lfw, afw,
                     vfw, Wq, bq, Wk, bk, Wv, bv, Wz, bz, Wff, bff, g1, be1,
                     g2, be2, Wp1, bp1, Wp2, bp2, out);
}

// Round 6
// 541.781 us; speedup vs baseline: 1.2052x; 1.2052x over previous
//
#include <hip/hip_runtime.h>

// ---------------------------------------------------------------------------
// Fused multimodal net: l-MLP + 2 LSTMs (MFMA bf16) + tiny transformer head.
// N=4096, T=256, DA=74, DV=47, hidden=32.
//
// LSTM: ONE wave per 16 samples owns all 32 units -> the h recurrence never
// leaves the wave => ZERO barriers in the 256-step loop. 512 independent
// 64-thread blocks (256 a + 256 v), each self-paced.
//   - x staged via global_load_lds into a wave-private 8-slot LDS ring,
//     issued 5 steps ahead, counted vmcnt(4*LPS) waits (never 0).
//   - 8 gate-tiles (16 rows = 4 gates x 4 units, row rho -> gate rho&3,
//     unit tau*4+(rho>>2)); lane (q,c) C-regs r=0..3 = i,f,g,o of unit
//     tau*4+q, sample c  => elementwise update lane-local.
//   - producer ring: during step t compute gx[t+1] = bias + Wih@x[t+1]
//     (24 off-chain MFMAs); on-chain per step: 8 h-MFMAs + trans + 8
//     ds_write_b16 + 1 ds_read_b128 (intra-wave, lgkmcnt-ordered).
// ---------------------------------------------------------------------------

typedef float float4v __attribute__((ext_vector_type(4)));
typedef float float2v __attribute__((ext_vector_type(2)));
typedef short short8v __attribute__((ext_vector_type(8)));

#define N_SAMPLES 4096
#define T_STEPS 256
#define HSTR 40  // shorts per sample row in H (32 units + pad to 80B)

__device__ __forceinline__ short bf16r(float f) {
  unsigned u = __float_as_uint(f);
  u += 0x7FFFu + ((u >> 16) & 1u);
  return (short)(u >> 16);
}
__device__ __forceinline__ unsigned cvt_pk_bf16(float lo, float hi) {
  unsigned r;
  asm("v_cvt_pk_bf16_f32 %0, %1, %2" : "=v"(r) : "v"(lo), "v"(hi));
  return r;
}
__device__ __forceinline__ float sigmoidf_(float v) {
  return __fdividef(1.0f, 1.0f + __expf(-v));
}
__device__ __forceinline__ float tanhf_fast(float v) {
  return 1.0f - __fdividef(2.0f, __expf(2.0f * v) + 1.0f);
}
__device__ __forceinline__ float4v mfma32(short8v a, short8v b, float4v c) {
  return __builtin_amdgcn_mfma_f32_16x16x32_bf16(a, b, c, 0, 0, 0);
}
__device__ __forceinline__ void gld16(const float* g, float* l) {
  __builtin_amdgcn_global_load_lds(
      (const __attribute__((address_space(1))) unsigned int*)g,
      (__attribute__((address_space(3))) unsigned int*)l, 16, 0, 0);
}

// LDS: x ring 8 * 16*74*4 = 37888 + H 16*80 = 1280 (+pad) => 39232
#define SMEM_BYTES (8 * 16 * 74 * 4 + 1280 + 64)

template <int D, int NK32, int LPS>
__device__ void lstm1w(const float* __restrict__ x,
                       const float* __restrict__ Wih,
                       const float* __restrict__ Whh,
                       const float* __restrict__ bih,
                       const float* __restrict__ bhh,
                       const float* __restrict__ Wo,
                       const float* __restrict__ bo,
                       float* __restrict__ outf, int n0, char* smem) {
  constexpr int FPS = 16 * D;    // floats per ring slot
  constexpr int UPS = FPS / 4;   // 16B units per slot
  constexpr int FULL = UPS / 64; // full gld16 rounds
  constexpr int REM = UPS % 64;

  float* xbuf = (float*)smem;                       // [8][FPS]
  unsigned short* Hu = (unsigned short*)(smem + 8 * FPS * 4);  // [16][HSTR]

  const int lane = threadIdx.x;  // 64-thread block = 1 wave
  const int c = lane & 15;       // sample col
  const int q = lane >> 4;       // k-octet selector

  // stage step t's x into ring slot t&7 (wave-private, linear dest)
  auto stageslot = [&](int t) {
    const float* gs = x + (size_t)t * (N_SAMPLES * D) + (size_t)n0 * D;
    float* ls = xbuf + (t & 7) * FPS;
#pragma unroll
    for (int r = 0; r < FULL; ++r)
      gld16(gs + (r * 64 + lane) * 4, ls + r * 256);
    if (REM) {
      if (lane < REM) gld16(gs + (FULL * 64 + lane) * 4, ls + FULL * 256);
    }
  };

  // prologue stage: slots 0..4 in flight (5*LPS loads)
  stageslot(0); stageslot(1); stageslot(2); stageslot(3); stageslot(4);

  // counted wait: slot (oldest) landed when <= 4*LPS outstanding
  auto waitx = [&]() {
    if constexpr (LPS == 5)
      asm volatile("s_waitcnt vmcnt(20)" ::: "memory");
    else
      asm volatile("s_waitcnt vmcnt(12)" ::: "memory");
    __builtin_amdgcn_sched_barrier(0);
  };

  // tail mask for last x k-tile (zero d >= D); dword j = elems 2j,2j+1
  unsigned mm[4];
#pragma unroll
  for (int j = 0; j < 4; ++j) {
    const int d0 = (NK32 - 1) * 32 + q * 8 + 2 * j;
    mm[j] = ((d0 < D) ? 0xFFFFu : 0u) | ((d0 + 1 < D) ? 0xFFFF0000u : 0u);
  }

  // stationary weights: 8 gate tiles (overlaps stage-0 HBM latency)
  short8v wfx[8][NK32], wfh[8];
  float4v binit[8];
#pragma unroll
  for (int T = 0; T < 8; ++T) {
    const int G = (c & 3) * 32 + T * 4 + (c >> 2);
    const float* wr = Wih + G * D;
#pragma unroll
    for (int kt = 0; kt < NK32; ++kt) {
      short8v s;
#pragma unroll
      for (int e = 0; e < 8; ++e) {
        const int d = kt * 32 + q * 8 + e;
        s[e] = (d < D) ? bf16r(wr[d]) : (short)0;
      }
      wfx[T][kt] = s;
    }
    const float* hr = Whh + G * 32;
#pragma unroll
    for (int e = 0; e < 8; ++e) wfh[T][e] = bf16r(hr[q * 8 + e]);
#pragma unroll
    for (int r = 0; r < 4; ++r) {
      const int Gr = r * 32 + T * 4 + q;  // C reg r -> gate r, unit T*4+q
      binit[T][r] = bih[Gr] + bhh[Gr];
    }
  }

  // read+convert slot s -> B-fragments
  auto ldcvt = [&](int slot, short8v* xo) {
    const float* xs = xbuf + slot * FPS + c * D;
#pragma unroll
    for (int kt = 0; kt < NK32; ++kt) {
      const float* p = xs + kt * 32 + q * 8;
      const float2v r0 = *(const float2v*)(p);
      const float2v r1 = *(const float2v*)(p + 2);
      const float2v r2 = *(const float2v*)(p + 4);
      const float2v r3 = *(const float2v*)(p + 6);
      union { short8v s; unsigned u[4]; } fr;
      fr.u[0] = cvt_pk_bf16(r0[0], r0[1]);
      fr.u[1] = cvt_pk_bf16(r1[0], r1[1]);
      fr.u[2] = cvt_pk_bf16(r2[0], r2[1]);
      fr.u[3] = cvt_pk_bf16(r3[0], r3[1]);
      if (kt == NK32 - 1) {
#pragma unroll
        for (int j = 0; j < 4; ++j) fr.u[j] &= mm[j];
      }
      xo[kt] = fr.s;
    }
  };

  float cst[8];
#pragma unroll
  for (int T = 0; T < 8; ++T) cst[T] = 0.0f;
  short8v hB = {0, 0, 0, 0, 0, 0, 0, 0};  // h[-1] = 0, register-resident

  float4v gA[8], gB[8];
  {
    waitx();  // slot 0 landed
    short8v xC[NK32];
    ldcvt(0, xC);
#pragma unroll
    for (int T = 0; T < 8; ++T) {
      float4v g4 = binit[T];
#pragma unroll
      for (int kt = 0; kt < NK32; ++kt) g4 = mfma32(wfx[T][kt], xC[kt], g4);
      gA[T] = g4;
    }
  }

  // one step: consume gc (gates for t), produce gn (gates for t+1)
  auto STEP = [&](int t, float4v (&gc)[8], float4v (&gn)[8]) {
    if (t + 5 < T_STEPS) stageslot(t + 5);
    waitx();  // slot t+1 landed (4 slots of loads remain outstanding)

    // off-chain: x[t+1] frags + production MFMAs
    short8v xN[NK32];
    ldcvt((t + 1) & 7, xN);

    // on-chain: 8 h-MFMAs (accumulate into gates of step t)
    float4v acc[8];
#pragma unroll
    for (int T = 0; T < 8; ++T) acc[T] = mfma32(wfh[T], hB, gc[T]);

#pragma unroll
    for (int T = 0; T < 8; ++T) {
      float4v g4 = binit[T];
#pragma unroll
      for (int kt = 0; kt < NK32; ++kt) g4 = mfma32(wfx[T][kt], xN[kt], g4);
      gn[T] = g4;
    }

    // lane-local update: unit T*4+q, gates in acc[T][0..3]
    unsigned short* hw = Hu + c * HSTR;
#pragma unroll
    for (int T = 0; T < 8; ++T) {
      const float iv = sigmoidf_(acc[T][0]);
      const float fv = sigmoidf_(acc[T][1]);
      const float gv = tanhf_fast(acc[T][2]);
      const float ov = sigmoidf_(acc[T][3]);
      const float cv = fv * cst[T] + iv * gv;
      cst[T] = cv;
      hw[T * 4 + q] = (unsigned short)bf16r(ov * tanhf_fast(cv));
    }
    // intra-wave: lgkmcnt orders writes before this read (no barrier)
    hB = *(const short8v*)(Hu + c * HSTR + q * 8);
  };

  for (int t = 0; t < T_STEPS; t += 2) {
    STEP(t, gA, gB);
    STEP(t + 1, gB, gA);
  }

  // epilogue: hB = h[255]; out = relu(h @ Wo^T + bo)
#pragma unroll
  for (int T2 = 0; T2 < 2; ++T2) {
    const float* wor = Wo + (16 * T2 + c) * 32;
    short8v w8;
#pragma unroll
    for (int e = 0; e < 8; ++e) w8[e] = bf16r(wor[q * 8 + e]);
    float4v o4 = {0.0f, 0.0f, 0.0f, 0.0f};
    o4 = mfma32(w8, hB, o4);
    float4v res;
#pragma unroll
    for (int r = 0; r < 4; ++r)
      res[r] = fmaxf(o4[r] + bo[16 * T2 + q * 4 + r], 0.0f);
    *(float4v*)(outf + (size_t)(n0 + c) * 32 + 16 * T2 + q * 4) = res;
  }
}

__global__ __launch_bounds__(64, 1) void lstm_both(
    const float* __restrict__ a, const float* __restrict__ v,
    const float* __restrict__ aWih, const float* __restrict__ aWhh,
    const float* __restrict__ abih, const float* __restrict__ abhh,
    const float* __restrict__ aWo, const float* __restrict__ abo,
    const float* __restrict__ vWih, const float* __restrict__ vWhh,
    const float* __restrict__ vbih, const float* __restrict__ vbhh,
    const float* __restrict__ vWo, const float* __restrict__ vbo,
    float* __restrict__ afw, float* __restrict__ vfw) {
  __shared__ __align__(16) char smem[SMEM_BYTES];
  const int b = blockIdx.x;
  if (b < 256)
    lstm1w<74, 3, 5>(a, aWih, aWhh, abih, abhh, aWo, abo, afw, b * 16, smem);
  else
    lstm1w<47, 2, 3>(v, vWih, vWhh, vbih, vbhh, vWo, vbo, vfw,
                     (b - 256) * 16, smem);
}

// ---------------------------------------------------------------------------
// lf = relu(relu(l @ lW1^T + lb1) @ lW2^T + lb2)   [4096,768]->[4096,32]
// ---------------------------------------------------------------------------
__global__ __launch_bounds__(256) void lf_kernel(
    const float* __restrict__ l, const float* __restrict__ lW1,
    const float* __restrict__ lb1, const float* __restrict__ lW2,
    const float* __restrict__ lb2, float* __restrict__ lf) {
  __shared__ __align__(16) float lsh[16 * 768];
  __shared__ __align__(16) float h1sh[16 * 128];
  const int tid = threadIdx.x;
  const int n0 = blockIdx.x * 16;

  {
    const float4v* src = (const float4v*)(l + (size_t)n0 * 768);
    float4v* dst = (float4v*)lsh;
#pragma unroll
    for (int i = 0; i < 12; ++i) dst[tid + i * 256] = src[tid + i * 256];
  }
  __syncthreads();

  {
    const int u = tid & 127;
    const int sg = tid >> 7;
    float acc[8];
#pragma unroll
    for (int i = 0; i < 8; ++i) acc[i] = 0.0f;
    const float4v* wrow = (const float4v*)(lW1 + u * 768);
    for (int k4 = 0; k4 < 192; ++k4) {
      const float4v w = wrow[k4];
#pragma unroll
      for (int i = 0; i < 8; ++i) {
        const float4v xv = ((const float4v*)(lsh + (sg * 8 + i) * 768))[k4];
        acc[i] += w[0] * xv[0] + w[1] * xv[1] + w[2] * xv[2] + w[3] * xv[3];
      }
    }
    const float b = lb1[u];
#pragma unroll
    for (int i = 0; i < 8; ++i)
      h1sh[(sg * 8 + i) * 128 + u] = fmaxf(acc[i] + b, 0.0f);
  }
  __syncthreads();

  {
    const int u2 = tid & 31;
    const int sg2 = tid >> 5;
    float acc0 = 0.0f, acc1 = 0.0f;
    const float4v* w2 = (const float4v*)(lW2 + u2 * 128);
#pragma unroll
    for (int k4 = 0; k4 < 32; ++k4) {
      const float4v w = w2[k4];
      const float4v xa = ((const float4v*)(h1sh + sg2 * 128))[k4];
      const float4v xb = ((const float4v*)(h1sh + (sg2 + 8) * 128))[k4];
      acc0 += w[0] * xa[0] + w[1] * xa[1] + w[2] * xa[2] + w[3] * xa[3];
      acc1 += w[0] * xb[0] + w[1] * xb[1] + w[2] * xb[2] + w[3] * xb[3];
    }
    const float b2 = lb2[u2];
    lf[(size_t)(n0 + sg2) * 32 + u2] = fmaxf(acc0 + b2, 0.0f);
    lf[(size_t)(n0 + sg2 + 8) * 32 + u2] = fmaxf(acc1 + b2, 0.0f);
  }
}

// ---------------------------------------------------------------------------
// Transformer block + post-fusion head. 32 lanes/sample, 8 samples/block.
// ---------------------------------------------------------------------------
__global__ __launch_bounds__(256) void head_kernel(
    const float* __restrict__ lf, const float* __restrict__ af,
    const float* __restrict__ vf, const float* __restrict__ Wq,
    const float* __restrict__ bq, const float* __restrict__ Wk,
    const float* __restrict__ bk, const float* __restrict__ Wv,
    const float* __restrict__ bv, const float* __restrict__ Wz,
    const float* __restrict__ bz, const float* __restrict__ Wff,
    const float* __restrict__ bff, const float* __restrict__ g1,
    const float* __restrict__ be1, const float* __restrict__ g2,
    const float* __restrict__ be2, const float* __restrict__ Wp1,
    const float* __restrict__ bp1, const float* __restrict__ Wp2,
    const float* __restrict__ bp2, float* __restrict__ out) {
  __shared__ float shA[8][3][33];
  __shared__ float shB[8][3][33];
  const int tid = threadIdx.x;
  const int j = tid & 31;
  const int slot = tid >> 5;
  const int n = blockIdx.x * 8 + slot;
  const size_t off = (size_t)n * 32 + j;

  const float x0 = lf[off], x1 = af[off], x2 = vf[off];

  auto ln3 = [&](float a0, float a1, float a2, const float* g,
                 const float* be, float* o) {
    float s = a0 + a1 + a2;
    s += __shfl_xor(s, 1); s += __shfl_xor(s, 2); s += __shfl_xor(s, 4);
    s += __shfl_xor(s, 8); s += __shfl_xor(s, 16);
    const float mu = s * (1.0f / 96.0f);
    const float d0 = a0 - mu, d1 = a1 - mu, d2 = a2 - mu;
    float ss = d0 * d0 + d1 * d1 + d2 * d2;
    ss += __shfl_xor(ss, 1); ss += __shfl_xor(ss, 2); ss += __shfl_xor(ss, 4);
    ss += __shfl_xor(ss, 8); ss += __shfl_xor(ss, 16);
    const float rs = rsqrtf(ss * (1.0f / 96.0f) + 1e-5f);
    o[0] = d0 * rs * g[j] + be[j];
    o[1] = d1 * rs * g[32 + j] + be[32 + j];
    o[2] = d2 * rs * g[64 + j] + be[64 + j];
  };

  float z[3];
  ln3(x0, x1, x2, g1, be1, z);
  shA[slot][0][j] = z[0]; shA[slot][1][j] = z[1]; shA[slot][2][j] = z[2];
  __syncthreads();

  float qv[3], kv[3], vv[3];
  {
    const float bqj = bq[j], bkj = bk[j], bvj = bv[j];
    qv[0] = bqj; qv[1] = bqj; qv[2] = bqj;
    kv[0] = bkj; kv[1] = bkj; kv[2] = bkj;
    vv[0] = bvj; vv[1] = bvj; vv[2] = bvj;
    const float* wqr = Wq + j * 32;
    const float* wkr = Wk + j * 32;
    const float* wvr = Wv + j * 32;
#pragma unroll 8
    for (int k = 0; k < 32; ++k) {
      const float zz0 = shA[slot][0][k], zz1 = shA[slot][1][k],
                  zz2 = shA[slot][2][k];
      const float wq = wqr[k], wk_ = wkr[k], wv_ = wvr[k];
      qv[0] += wq * zz0;  qv[1] += wq * zz1;  qv[2] += wq * zz2;
      kv[0] += wk_ * zz0; kv[1] += wk_ * zz1; kv[2] += wk_ * zz2;
      vv[0] += wv_ * zz0; vv[1] += wv_ * zz1; vv[2] += wv_ * zz2;
    }
  }

  float at[3][3];
#pragma unroll
  for (int s = 0; s < 3; ++s)
#pragma unroll
    for (int t2 = 0; t2 < 3; ++t2) {
      float p = qv[s] * kv[t2];
      p += __shfl_xor(p, 1); p += __shfl_xor(p, 2); p += __shfl_xor(p, 4);
      at[s][t2] = p;
    }
#pragma unroll
  for (int s = 0; s < 3; ++s) {
    const float m = fmaxf(fmaxf(at[s][0], at[s][1]), at[s][2]);
    const float e0 = __expf(at[s][0] - m), e1 = __expf(at[s][1] - m),
                e2 = __expf(at[s][2] - m);
    const float sc = 0.35355339059327373f * __fdividef(1.0f, e0 + e1 + e2);
    at[s][0] = e0 * sc; at[s][1] = e1 * sc; at[s][2] = e2 * sc;
  }
  float zc[3];
#pragma unroll
  for (int s = 0; s < 3; ++s)
    zc[s] = at[s][0] * vv[0] + at[s][1] * vv[1] + at[s][2] * vv[2];
  shB[slot][0][j] = zc[0]; shB[slot][1][j] = zc[1]; shB[slot][2][j] = zc[2];
  __syncthreads();

  const float bzj = bz[j];
  float z2a[3] = {bzj + x0, bzj + x1, bzj + x2};
  {
    const float* wzr = Wz + j * 32;
#pragma unroll 8
    for (int k = 0; k < 32; ++k) {
      const float w = wzr[k];
      z2a[0] += w * shB[slot][0][k];
      z2a[1] += w * shB[slot][1][k];
      z2a[2] += w * shB[slot][2][k];
    }
  }

  float zn[3];
  ln3(z2a[0], z2a[1], z2a[2], g2, be2, zn);
  shA[slot][0][j] = zn[0]; shA[slot][1][j] = zn[1]; shA[slot][2][j] = zn[2];
  __syncthreads();

  const float bffj = bff[j];
  float Za[3] = {bffj + z2a[0], bffj + z2a[1], bffj + z2a[2]};
  {
    const float* wfr = Wff + j * 32;
#pragma unroll 8
    for (int k = 0; k < 32; ++k) {
      const float w = wfr[k];
      Za[0] += w * shA[slot][0][k];
      Za[1] += w * shA[slot][1][k];
      Za[2] += w * shA[slot][2][k];
    }
  }
  shB[slot][0][j] = Za[0]; shB[slot][1][j] = Za[1]; shB[slot][2][j] = Za[2];
  __syncthreads();

  float p = bp1[j];
  {
    const float* wpr = Wp1 + j * 96;
#pragma unroll
    for (int s = 0; s < 3; ++s)
#pragma unroll 8
      for (int k = 0; k < 32; ++k) p += wpr[s * 32 + k] * shB[slot][s][k];
  }
  p = fmaxf(p, 0.0f);
  float l0 = Wp2[j] * p, l1 = Wp2[32 + j] * p;
  l0 += __shfl_xor(l0, 1); l0 += __shfl_xor(l0, 2); l0 += __shfl_xor(l0, 4);
  l0 += __shfl_xor(l0, 8); l0 += __shfl_xor(l0, 16);
  l1 += __shfl_xor(l1, 1); l1 += __shfl_xor(l1, 2); l1 += __shfl_xor(l1, 4);
  l1 += __shfl_xor(l1, 8); l1 += __shfl_xor(l1, 16);
  l0 += bp2[0]; l1 += bp2[1];
  const float mx = fmaxf(l0, l1);
  const float e0 = __expf(l0 - mx), e1 = __expf(l1 - mx);
  const float inv = __fdividef(1.0f, e0 + e1);
  if (j == 0) {
    out[(size_t)n * 2 + 0] = e0 * inv;
    out[(size_t)n * 2 + 1] = e1 * inv;
  }
}

// ---------------------------------------------------------------------------
extern "C" void kernel_launch(void* const* d_in, const int* in_sizes, int n_in,
                              void* d_out, int out_size, void* d_ws,
                              size_t ws_size, hipStream_t stream) {
  const float* l    = (const float*)d_in[0];
  const float* a    = (const float*)d_in[1];
  const float* v    = (const float*)d_in[2];
  const float* lW1  = (const float*)d_in[3];
  const float* lb1  = (const float*)d_in[4];
  const float* lW2  = (const float*)d_in[5];
  const float* lb2  = (const float*)d_in[6];
  const float* aWih = (const float*)d_in[7];
  const float* aWhh = (const float*)d_in[8];
  const float* abih = (const float*)d_in[9];
  const float* abhh = (const float*)d_in[10];
  const float* aWo  = (const float*)d_in[11];
  const float* abo  = (const float*)d_in[12];
  const float* vWih = (const float*)d_in[13];
  const float* vWhh = (const float*)d_in[14];
  const float* vbih = (const float*)d_in[15];
  const float* vbhh = (const float*)d_in[16];
  const float* vWo  = (const float*)d_in[17];
  const float* vbo  = (const float*)d_in[18];
  const float* Wq   = (const float*)d_in[19];
  const float* bq   = (const float*)d_in[20];
  const float* Wk   = (const float*)d_in[21];
  const float* bk   = (const float*)d_in[22];
  const float* Wv   = (const float*)d_in[23];
  const float* bv   = (const float*)d_in[24];
  const float* Wz   = (const float*)d_in[25];
  const float* bz   = (const float*)d_in[26];
  const float* Wff  = (const float*)d_in[27];
  const float* bff  = (const float*)d_in[28];
  const float* g1   = (const float*)d_in[29];
  const float* be1  = (const float*)d_in[30];
  const float* g2   = (const float*)d_in[31];
  const float* be2  = (const float*)d_in[32];
  const float* Wp1  = (const float*)d_in[33];
  const float* bp1  = (const float*)d_in[34];
  const float* Wp2  = (const float*)d_in[35];
  const float* bp2  = (const float*)d_in[36];

  float* out = (float*)d_out;
  float* ws = (float*)d_ws;
  float* lfw = ws;
  float* afw = ws + 4096 * 32;
  float* vfw = ws + 2 * 4096 * 32;

  hipLaunchKernelGGL(lstm_both, dim3(512), dim3(64), 0, stream, a, v, aWih,
                     aWhh, abih, abhh, aWo, abo, vWih, vWhh, vbih, vbhh, vWo,
                     vbo, afw, vfw);
  hipLaunchKernelGGL(lf_kernel, dim3(256), dim3(256), 0, stream, l, lW1, lb1,
                     lW2, lb2, lfw);
  hipLaunchKernelGGL(head_kernel, dim3(512), dim3(256), 0, stream, lfw, afw,
                     vfw, Wq, bq, Wk, bk, Wv, bv, Wz, bz, Wff, bff, g1, be1,
                     g2, be2, Wp1, bp1, Wp2, bp2, out);
}

// Round 7
// 360.437 us; speedup vs baseline: 1.8116x; 1.5031x over previous
//
#include <hip/hip_runtime.h>

// ---------------------------------------------------------------------------
// Fused multimodal net: l-MLP + 2 LSTMs (MFMA bf16, LDS-staged) + tiny
// transformer head. N=4096, T=256, DA=74, DV=47, hidden=32.
//
// LSTM: block = 128 threads = 2 waves per 16-sample group -> 1024 waves
// chip-wide (1/SIMD). Row map: gate row G = r*32 + wid*16 + q*4 + tau, so
// lane (q,c) tile tau C-regs 0..3 = i,f,g,o of unit wid*16+q*4+tau -> the
// lane's 4 h values are CONTIGUOUS shorts => 2 cvt_pk + 1 ds_write_b64.
// Producer ring: step t produces gx[t+1] = bias + Wih@x[t+1] (12 off-chain
// MFMAs); on-chain: 1 ds_read_b128 (h) + 4 h-MFMAs + lean trans + b64 write
// + lgkm + 2-wave s_barrier.
// x staged via global_load_lds 8-slot ring, slot t+5 issued at step t by
// wave (t+5)&1; counted vmcnt(LPS) at step end guarantees slot t+1 landed
// (loader's newest slot then is t+3). 8-step unroll => static addressing.
// ---------------------------------------------------------------------------

typedef float float4v __attribute__((ext_vector_type(4)));
typedef float float2v __attribute__((ext_vector_type(2)));
typedef short short8v __attribute__((ext_vector_type(8)));
typedef unsigned uint2v __attribute__((ext_vector_type(2)));

#define N_SAMPLES 4096
#define T_STEPS 256
#define HSTR 40           // shorts per sample row in H (32 units + pad)
#define HBUF (16 * HSTR)  // shorts per H buffer

#define LGKM0 asm volatile("s_waitcnt lgkmcnt(0)" ::: "memory")

__device__ __forceinline__ short bf16r(float f) {
  unsigned u = __float_as_uint(f);
  u += 0x7FFFu + ((u >> 16) & 1u);
  return (short)(u >> 16);
}
__device__ __forceinline__ unsigned cvt_pk_bf16(float lo, float hi) {
  unsigned r;
  asm("v_cvt_pk_bf16_f32 %0, %1, %2" : "=v"(r) : "v"(lo), "v"(hi));
  return r;
}
__device__ __forceinline__ float exp2v(float x) {
  float r;
  asm("v_exp_f32 %0, %1" : "=v"(r) : "v"(x));
  return r;
}
__device__ __forceinline__ float rcpv(float x) {
  float r;
  asm("v_rcp_f32 %0, %1" : "=v"(r) : "v"(x));
  return r;
}
// sigmoid(x) = 1/(1+2^(-x*log2e))
__device__ __forceinline__ float sigm_(float x) {
  return rcpv(1.0f + exp2v(x * -1.44269504f));
}
// tanh(x) = 1 - 2/(2^(x*2*log2e)+1)
__device__ __forceinline__ float tanh_(float x) {
  return 1.0f - 2.0f * rcpv(1.0f + exp2v(x * 2.88539009f));
}
__device__ __forceinline__ float4v mfma32(short8v a, short8v b, float4v c) {
  return __builtin_amdgcn_mfma_f32_16x16x32_bf16(a, b, c, 0, 0, 0);
}
__device__ __forceinline__ void gld16(const float* g, float* l) {
  __builtin_amdgcn_global_load_lds(
      (const __attribute__((address_space(1))) unsigned int*)g,
      (__attribute__((address_space(3))) unsigned int*)l, 16, 0, 0);
}

// LDS: x ring 8*16*74*4 = 37888 + H 2*640*2 = 2560 + pad => 40512
#define SMEM_BYTES (8 * 16 * 74 * 4 + 2 * HBUF * 2 + 64)

template <int D, int NK32, int LPS>
__device__ void lstm2w(const float* __restrict__ x,
                       const float* __restrict__ Wih,
                       const float* __restrict__ Whh,
                       const float* __restrict__ bih,
                       const float* __restrict__ bhh,
                       const float* __restrict__ Wo,
                       const float* __restrict__ bo,
                       float* __restrict__ outf, int n0, char* smem) {
  constexpr int FPS = 16 * D;    // floats per ring slot
  constexpr int UPS = FPS / 4;   // 16B units per slot
  constexpr int FULL = UPS / 64;
  constexpr int REM = UPS % 64;

  float* xbuf = (float*)smem;                                   // [8][FPS]
  unsigned short* Hu = (unsigned short*)(smem + 8 * FPS * 4);   // [2][16][40]

  const int tid = threadIdx.x;
  const int wid = tid >> 6;   // 0..1
  const int lane = tid & 63;
  const int c = lane & 15;
  const int q = lane >> 4;

  auto stageslot = [&](int t) {
    const float* gs = x + (size_t)t * (N_SAMPLES * D) + (size_t)n0 * D;
    float* ls = xbuf + (t & 7) * FPS;
#pragma unroll
    for (int r = 0; r < FULL; ++r)
      gld16(gs + (r * 64 + lane) * 4, ls + r * 256);
    if (REM) {
      if (lane < REM) gld16(gs + (FULL * 64 + lane) * 4, ls + FULL * 256);
    }
  };

  // prologue staging: wave0 -> slots 0,2,4 ; wave1 -> slots 1,3
  if (wid == 0) { stageslot(0); stageslot(2); stageslot(4); }
  else          { stageslot(1); stageslot(3); }

  // tail mask for last x k-tile
  unsigned mm[4];
#pragma unroll
  for (int j = 0; j < 4; ++j) {
    const int d0 = (NK32 - 1) * 32 + q * 8 + 2 * j;
    mm[j] = ((d0 < D) ? 0xFFFFu : 0u) | ((d0 + 1 < D) ? 0xFFFF0000u : 0u);
  }

  // stationary weights: 4 tiles (16 units) per wave
  short8v wfx[4][NK32], wfh[4];
  float4v binit[4];
#pragma unroll
  for (int T = 0; T < 4; ++T) {
    const int G = (c & 3) * 32 + wid * 16 + (c >> 2) * 4 + T;  // A-row c
    const float* wr = Wih + G * D;
#pragma unroll
    for (int kt = 0; kt < NK32; ++kt) {
      short8v s;
#pragma unroll
      for (int e = 0; e < 8; ++e) {
        const int d = kt * 32 + q * 8 + e;
        s[e] = (d < D) ? bf16r(wr[d]) : (short)0;
      }
      wfx[T][kt] = s;
    }
    const float* hr = Whh + G * 32;
#pragma unroll
    for (int e = 0; e < 8; ++e) wfh[T][e] = bf16r(hr[q * 8 + e]);
#pragma unroll
    for (int r = 0; r < 4; ++r) {
      const int Gr = r * 32 + wid * 16 + q * 4 + T;  // C reg r mapping
      binit[T][r] = bih[Gr] + bhh[Gr];
    }
  }

  // zero both H buffers (1280 dwords? 2*640 shorts*2 = 2560B = 640 dwords)
  {
    unsigned* Hz = (unsigned*)Hu;
    for (int i = tid; i < 640; i += 128) Hz[i] = 0;
  }

  // prologue waits: wave0 ensure slot0, wave1 ensure slot1
  if (wid == 0) {
    if constexpr (LPS == 5) asm volatile("s_waitcnt vmcnt(10)" ::: "memory");
    else                    asm volatile("s_waitcnt vmcnt(6)" ::: "memory");
  } else {
    if constexpr (LPS == 5) asm volatile("s_waitcnt vmcnt(5)" ::: "memory");
    else                    asm volatile("s_waitcnt vmcnt(3)" ::: "memory");
  }
  LGKM0;
  __builtin_amdgcn_s_barrier();

  auto ldcvt = [&](const float* xs0, short8v* xo) {
    const float* xs = xs0 + c * D;
#pragma unroll
    for (int kt = 0; kt < NK32; ++kt) {
      const float* p = xs + kt * 32 + q * 8;
      const float2v r0 = *(const float2v*)(p);
      const float2v r1 = *(const float2v*)(p + 2);
      const float2v r2 = *(const float2v*)(p + 4);
      const float2v r3 = *(const float2v*)(p + 6);
      union { short8v s; unsigned u[4]; } fr;
      fr.u[0] = cvt_pk_bf16(r0[0], r0[1]);
      fr.u[1] = cvt_pk_bf16(r1[0], r1[1]);
      fr.u[2] = cvt_pk_bf16(r2[0], r2[1]);
      fr.u[3] = cvt_pk_bf16(r3[0], r3[1]);
      if (mm[0] != 0xFFFFFFFFu || mm[3] != 0xFFFFFFFFu) {
#pragma unroll
        for (int j = 0; j < 4; ++j) fr.u[j] &= mm[j];
      }
      xo[kt] = fr.s;
    }
  };

  float cst[4] = {0.0f, 0.0f, 0.0f, 0.0f};
  float4v gxA[4], gxB[4];
  {
    short8v xF[NK32];
    ldcvt(xbuf, xF);  // slot 0 = x[0]
#pragma unroll
    for (int T = 0; T < 4; ++T) {
      float4v g4 = binit[T];
#pragma unroll
      for (int kt = 0; kt < NK32; ++kt) g4 = mfma32(wfx[T][kt], xF[kt], g4);
      gxA[T] = g4;
    }
  }

  // one step; i = t&7 compile-time, gc = gates for t, gn -> gates for t+1
  auto STEP = [&](int t, int i, float4v (&gc)[4], float4v (&gn)[4]) {
    const int pb = i & 1;
    // on-chain: h of step t-1 (all 32 units)
    const short8v hB = *(const short8v*)(Hu + pb * HBUF + c * HSTR + q * 8);
    // staging (alternating waves), slot (i+5)&7
    if (((i + 5) & 1) == wid && t + 5 < T_STEPS) stageslot(t + 5);
    // off-chain: x[t+1] frags + production
    short8v xN[NK32];
    ldcvt(xbuf + ((i + 1) & 7) * FPS, xN);
#pragma unroll
    for (int T = 0; T < 4; ++T) {
      float4v g4 = binit[T];
#pragma unroll
      for (int kt = 0; kt < NK32; ++kt) g4 = mfma32(wfx[T][kt], xN[kt], g4);
      gn[T] = g4;
    }
    // on-chain: 4 h-MFMAs + lean trans
    float hv[4];
#pragma unroll
    for (int T = 0; T < 4; ++T) {
      const float4v acc = mfma32(wfh[T], hB, gc[T]);
      const float iv = sigm_(acc[0]);
      const float fv = sigm_(acc[1]);
      const float gv = tanh_(acc[2]);
      const float ov = sigm_(acc[3]);
      const float cv = fv * cst[T] + iv * gv;
      cst[T] = cv;
      hv[T] = ov * tanh_(cv);
    }
    uint2v hp;
    hp[0] = cvt_pk_bf16(hv[0], hv[1]);
    hp[1] = cvt_pk_bf16(hv[2], hv[3]);
    *(uint2v*)(Hu + (1 - pb) * HBUF + c * HSTR + wid * 16 + q * 4) = hp;
    LGKM0;  // h write (and ds reads) done
    if constexpr (LPS == 5) asm volatile("s_waitcnt vmcnt(5)" ::: "memory");
    else                    asm volatile("s_waitcnt vmcnt(3)" ::: "memory");
    __builtin_amdgcn_s_barrier();
  };

  for (int tb = 0; tb < T_STEPS; tb += 8) {
    STEP(tb + 0, 0, gxA, gxB);
    STEP(tb + 1, 1, gxB, gxA);
    STEP(tb + 2, 2, gxA, gxB);
    STEP(tb + 3, 3, gxB, gxA);
    STEP(tb + 4, 4, gxA, gxB);
    STEP(tb + 5, 5, gxB, gxA);
    STEP(tb + 6, 6, gxA, gxB);
    STEP(tb + 7, 7, gxB, gxA);
  }

  // epilogue: h[255] in H buffer 0 (t=255 odd writes pb^1=0)
  {
    const short8v hB = *(const short8v*)(Hu + c * HSTR + q * 8);
    const float* wor = Wo + (16 * wid + c) * 32;
    short8v w8;
#pragma unroll
    for (int e = 0; e < 8; ++e) w8[e] = bf16r(wor[q * 8 + e]);
    float4v o4 = {0.0f, 0.0f, 0.0f, 0.0f};
    o4 = mfma32(w8, hB, o4);
    float4v res;
#pragma unroll
    for (int r = 0; r < 4; ++r)
      res[r] = fmaxf(o4[r] + bo[16 * wid + q * 4 + r], 0.0f);
    *(float4v*)(outf + (size_t)(n0 + c) * 32 + 16 * wid + q * 4) = res;
  }
}

__global__ __launch_bounds__(128) void lstm_both(
    const float* __restrict__ a, const float* __restrict__ v,
    const float* __restrict__ aWih, const float* __restrict__ aWhh,
    const float* __restrict__ abih, const float* __restrict__ abhh,
    const float* __restrict__ aWo, const float* __restrict__ abo,
    const float* __restrict__ vWih, const float* __restrict__ vWhh,
    const float* __restrict__ vbih, const float* __restrict__ vbhh,
    const float* __restrict__ vWo, const float* __restrict__ vbo,
    float* __restrict__ afw, float* __restrict__ vfw) {
  __shared__ __align__(16) char smem[SMEM_BYTES];
  const int b = blockIdx.x;
  if (b < 256)
    lstm2w<74, 3, 5>(a, aWih, aWhh, abih, abhh, aWo, abo, afw, b * 16, smem);
  else
    lstm2w<47, 2, 3>(v, vWih, vWhh, vbih, vbhh, vWo, vbo, vfw,
                     (b - 256) * 16, smem);
}

// ---------------------------------------------------------------------------
// lf = relu(relu(l @ lW1^T + lb1) @ lW2^T + lb2)   [4096,768]->[4096,32]
// ---------------------------------------------------------------------------
__global__ __launch_bounds__(256) void lf_kernel(
    const float* __restrict__ l, const float* __restrict__ lW1,
    const float* __restrict__ lb1, const float* __restrict__ lW2,
    const float* __restrict__ lb2, float* __restrict__ lf) {
  __shared__ __align__(16) float lsh[16 * 768];
  __shared__ __align__(16) float h1sh[16 * 128];
  const int tid = threadIdx.x;
  const int n0 = blockIdx.x * 16;

  {
    const float4v* src = (const float4v*)(l + (size_t)n0 * 768);
    float4v* dst = (float4v*)lsh;
#pragma unroll
    for (int i = 0; i < 12; ++i) dst[tid + i * 256] = src[tid + i * 256];
  }
  __syncthreads();

  {
    const int u = tid & 127;
    const int sg = tid >> 7;
    float acc[8];
#pragma unroll
    for (int i = 0; i < 8; ++i) acc[i] = 0.0f;
    const float4v* wrow = (const float4v*)(lW1 + u * 768);
    for (int k4 = 0; k4 < 192; ++k4) {
      const float4v w = wrow[k4];
#pragma unroll
      for (int i = 0; i < 8; ++i) {
        const float4v xv = ((const float4v*)(lsh + (sg * 8 + i) * 768))[k4];
        acc[i] += w[0] * xv[0] + w[1] * xv[1] + w[2] * xv[2] + w[3] * xv[3];
      }
    }
    const float b = lb1[u];
#pragma unroll
    for (int i = 0; i < 8; ++i)
      h1sh[(sg * 8 + i) * 128 + u] = fmaxf(acc[i] + b, 0.0f);
  }
  __syncthreads();

  {
    const int u2 = tid & 31;
    const int sg2 = tid >> 5;
    float acc0 = 0.0f, acc1 = 0.0f;
    const float4v* w2 = (const float4v*)(lW2 + u2 * 128);
#pragma unroll
    for (int k4 = 0; k4 < 32; ++k4) {
      const float4v w = w2[k4];
      const float4v xa = ((const float4v*)(h1sh + sg2 * 128))[k4];
      const float4v xb = ((const float4v*)(h1sh + (sg2 + 8) * 128))[k4];
      acc0 += w[0] * xa[0] + w[1] * xa[1] + w[2] * xa[2] + w[3] * xa[3];
      acc1 += w[0] * xb[0] + w[1] * xb[1] + w[2] * xb[2] + w[3] * xb[3];
    }
    const float b2 = lb2[u2];
    lf[(size_t)(n0 + sg2) * 32 + u2] = fmaxf(acc0 + b2, 0.0f);
    lf[(size_t)(n0 + sg2 + 8) * 32 + u2] = fmaxf(acc1 + b2, 0.0f);
  }
}

// ---------------------------------------------------------------------------
// Transformer block + post-fusion head. 32 lanes/sample, 8 samples/block.
// ---------------------------------------------------------------------------
__global__ __launch_bounds__(256) void head_kernel(
    const float* __restrict__ lf, const float* __restrict__ af,
    const float* __restrict__ vf, const float* __restrict__ Wq,
    const float* __restrict__ bq, const float* __restrict__ Wk,
    const float* __restrict__ bk, const float* __restrict__ Wv,
    const float* __restrict__ bv, const float* __restrict__ Wz,
    const float* __restrict__ bz, const float* __restrict__ Wff,
    const float* __restrict__ bff, const float* __restrict__ g1,
    const float* __restrict__ be1, const float* __restrict__ g2,
    const float* __restrict__ be2, const float* __restrict__ Wp1,
    const float* __restrict__ bp1, const float* __restrict__ Wp2,
    const float* __restrict__ bp2, float* __restrict__ out) {
  __shared__ float shA[8][3][33];
  __shared__ float shB[8][3][33];
  const int tid = threadIdx.x;
  const int j = tid & 31;
  const int slot = tid >> 5;
  const int n = blockIdx.x * 8 + slot;
  const size_t off = (size_t)n * 32 + j;

  const float x0 = lf[off], x1 = af[off], x2 = vf[off];

  auto ln3 = [&](float a0, float a1, float a2, const float* g,
                 const float* be, float* o) {
    float s = a0 + a1 + a2;
    s += __shfl_xor(s, 1); s += __shfl_xor(s, 2); s += __shfl_xor(s, 4);
    s += __shfl_xor(s, 8); s += __shfl_xor(s, 16);
    const float mu = s * (1.0f / 96.0f);
    const float d0 = a0 - mu, d1 = a1 - mu, d2 = a2 - mu;
    float ss = d0 * d0 + d1 * d1 + d2 * d2;
    ss += __shfl_xor(ss, 1); ss += __shfl_xor(ss, 2); ss += __shfl_xor(ss, 4);
    ss += __shfl_xor(ss, 8); ss += __shfl_xor(ss, 16);
    const float rs = rsqrtf(ss * (1.0f / 96.0f) + 1e-5f);
    o[0] = d0 * rs * g[j] + be[j];
    o[1] = d1 * rs * g[32 + j] + be[32 + j];
    o[2] = d2 * rs * g[64 + j] + be[64 + j];
  };

  float z[3];
  ln3(x0, x1, x2, g1, be1, z);
  shA[slot][0][j] = z[0]; shA[slot][1][j] = z[1]; shA[slot][2][j] = z[2];
  __syncthreads();

  float qv[3], kv[3], vv[3];
  {
    const float bqj = bq[j], bkj = bk[j], bvj = bv[j];
    qv[0] = bqj; qv[1] = bqj; qv[2] = bqj;
    kv[0] = bkj; kv[1] = bkj; kv[2] = bkj;
    vv[0] = bvj; vv[1] = bvj; vv[2] = bvj;
    const float* wqr = Wq + j * 32;
    const float* wkr = Wk + j * 32;
    const float* wvr = Wv + j * 32;
#pragma unroll 8
    for (int k = 0; k < 32; ++k) {
      const float zz0 = shA[slot][0][k], zz1 = shA[slot][1][k],
                  zz2 = shA[slot][2][k];
      const float wq = wqr[k], wk_ = wkr[k], wv_ = wvr[k];
      qv[0] += wq * zz0;  qv[1] += wq * zz1;  qv[2] += wq * zz2;
      kv[0] += wk_ * zz0; kv[1] += wk_ * zz1; kv[2] += wk_ * zz2;
      vv[0] += wv_ * zz0; vv[1] += wv_ * zz1; vv[2] += wv_ * zz2;
    }
  }

  float at[3][3];
#pragma unroll
  for (int s = 0; s < 3; ++s)
#pragma unroll
    for (int t2 = 0; t2 < 3; ++t2) {
      float p = qv[s] * kv[t2];
      p += __shfl_xor(p, 1); p += __shfl_xor(p, 2); p += __shfl_xor(p, 4);
      at[s][t2] = p;
    }
#pragma unroll
  for (int s = 0; s < 3; ++s) {
    const float m = fmaxf(fmaxf(at[s][0], at[s][1]), at[s][2]);
    const float e0 = __expf(at[s][0] - m), e1 = __expf(at[s][1] - m),
                e2 = __expf(at[s][2] - m);
    const float sc = 0.35355339059327373f * __fdividef(1.0f, e0 + e1 + e2);
    at[s][0] = e0 * sc; at[s][1] = e1 * sc; at[s][2] = e2 * sc;
  }
  float zc[3];
#pragma unroll
  for (int s = 0; s < 3; ++s)
    zc[s] = at[s][0] * vv[0] + at[s][1] * vv[1] + at[s][2] * vv[2];
  shB[slot][0][j] = zc[0]; shB[slot][1][j] = zc[1]; shB[slot][2][j] = zc[2];
  __syncthreads();

  const float bzj = bz[j];
  float z2a[3] = {bzj + x0, bzj + x1, bzj + x2};
  {
    const float* wzr = Wz + j * 32;
#pragma unroll 8
    for (int k = 0; k < 32; ++k) {
      const float w = wzr[k];
      z2a[0] += w * shB[slot][0][k];
      z2a[1] += w * shB[slot][1][k];
      z2a[2] += w * shB[slot][2][k];
    }
  }

  float zn[3];
  ln3(z2a[0], z2a[1], z2a[2], g2, be2, zn);
  shA[slot][0][j] = zn[0]; shA[slot][1][j] = zn[1]; shA[slot][2][j] = zn[2];
  __syncthreads();

  const float bffj = bff[j];
  float Za[3] = {bffj + z2a[0], bffj + z2a[1], bffj + z2a[2]};
  {
    const float* wfr = Wff + j * 32;
#pragma unroll 8
    for (int k = 0; k < 32; ++k) {
      const float w = wfr[k];
      Za[0] += w * shA[slot][0][k];
      Za[1] += w * shA[slot][1][k];
      Za[2] += w * shA[slot][2][k];
    }
  }
  shB[slot][0][j] = Za[0]; shB[slot][1][j] = Za[1]; shB[slot][2][j] = Za[2];
  __syncthreads();

  float p = bp1[j];
  {
    const float* wpr = Wp1 + j * 96;
#pragma unroll
    for (int s = 0; s < 3; ++s)
#pragma unroll 8
      for (int k = 0; k < 32; ++k) p += wpr[s * 32 + k] * shB[slot][s][k];
  }
  p = fmaxf(p, 0.0f);
  float l0 = Wp2[j] * p, l1 = Wp2[32 + j] * p;
  l0 += __shfl_xor(l0, 1); l0 += __shfl_xor(l0, 2); l0 += __shfl_xor(l0, 4);
  l0 += __shfl_xor(l0, 8); l0 += __shfl_xor(l0, 16);
  l1 += __shfl_xor(l1, 1); l1 += __shfl_xor(l1, 2); l1 += __shfl_xor(l1, 4);
  l1 += __shfl_xor(l1, 8); l1 += __shfl_xor(l1, 16);
  l0 += bp2[0]; l1 += bp2[1];
  const float mx = fmaxf(l0, l1);
  const float e0 = __expf(l0 - mx), e1 = __expf(l1 - mx);
  const float inv = __fdividef(1.0f, e0 + e1);
  if (j == 0) {
    out[(size_t)n * 2 + 0] = e0 * inv;
    out[(size_t)n * 2 + 1] = e1 * inv;
  }
}

// ---------------------------------------------------------------------------
extern "C" void kernel_launch(void* const* d_in, const int* in_sizes, int n_in,
                              void* d_out, int out_size, void* d_ws,
                              size_t ws_size, hipStream_t stream) {
  const float* l    = (const float*)d_in[0];
  const float* a    = (const float*)d_in[1];
  const float* v    = (const float*)d_in[2];
  const float* lW1  = (const float*)d_in[3];
  const float* lb1  = (const float*)d_in[4];
  const float* lW2  = (const float*)d_in[5];
  const float* lb2  = (const float*)d_in[6];
  const float* aWih = (const float*)d_in[7];
  const float* aWhh = (const float*)d_in[8];
  const float* abih = (const float*)d_in[9];
  const float* abhh = (const float*)d_in[10];
  const float* aWo  = (const float*)d_in[11];
  const float* abo  = (const float*)d_in[12];
  const float* vWih = (const float*)d_in[13];
  const float* vWhh = (const float*)d_in[14];
  const float* vbih = (const float*)d_in[15];
  const float* vbhh = (const float*)d_in[16];
  const float* vWo  = (const float*)d_in[17];
  const float* vbo  = (const float*)d_in[18];
  const float* Wq   = (const float*)d_in[19];
  const float* bq   = (const float*)d_in[20];
  const float* Wk   = (const float*)d_in[21];
  const float* bk   = (const float*)d_in[22];
  const float* Wv   = (const float*)d_in[23];
  const float* bv   = (const float*)d_in[24];
  const float* Wz   = (const float*)d_in[25];
  const float* bz   = (const float*)d_in[26];
  const float* Wff  = (const float*)d_in[27];
  const float* bff  = (const float*)d_in[28];
  const float* g1   = (const float*)d_in[29];
  const float* be1  = (const float*)d_in[30];
  const float* g2   = (const float*)d_in[31];
  const float* be2  = (const float*)d_in[32];
  const float* Wp1  = (const float*)d_in[33];
  const float* bp1  = (const float*)d_in[34];
  const float* Wp2  = (const float*)d_in[35];
  const float* bp2  = (const float*)d_in[36];

  float* out = (float*)d_out;
  float* ws = (float*)d_ws;
  float* lfw = ws;
  float* afw = ws + 4096 * 32;
  float* vfw = ws + 2 * 4096 * 32;

  hipLaunchKernelGGL(lstm_both, dim3(512), dim3(128), 0, stream, a, v, aWih,
                     aWhh, abih, abhh, aWo, abo, vWih, vWhh, vbih, vbhh, vWo,
                     vbo, afw, vfw);
  hipLaunchKernelGGL(lf_kernel, dim3(256), dim3(256), 0, stream, l, lW1, lb1,
                     lW2, lb2, lfw);
  hipLaunchKernelGGL(head_kernel, dim3(512), dim3(256), 0, stream, lfw, afw,
                     vfw, Wq, bq, Wk, bk, Wv, bv, Wz, bz, Wff, bff, g1, be1,
                     g2, be2, Wp1, bp1, Wp2, bp2, out);
}

// Round 8
// 310.554 us; speedup vs baseline: 2.1026x; 1.1606x over previous
//
#include <hip/hip_runtime.h>

// ---------------------------------------------------------------------------
// Fused multimodal net: l-MLP + 2 LSTMs (MFMA bf16, LDS-staged) + tiny
// transformer head. N=4096, T=256, DA=74, DV=47, hidden=32.
//
// LSTM: block = 128 threads = 2 waves per 16-sample group -> 1024 waves
// chip-wide (1/SIMD). Row map: gate row G = r*32 + wid*16 + q*4 + tau ->
// lane (q,c) tile tau C-regs 0..3 = i,f,g,o of unit wid*16+q*4+tau; the
// lane's 4 h values are contiguous shorts => 2 cvt_pk + 1 ds_write_b64.
// Producer ring: step t produces gx[t+1] = bias + Wih@x[t+1] (12 off-chain
// MFMAs); on-chain: 1 ds_read_b128 (h) + 4 h-MFMAs + lean trans + b64 write
// + lgkm + 2-wave s_barrier. x tail needs NO mask: weight fragments carry
// zeros for d>=D and all over-read LDS holds finite staged data.
// x staged via global_load_lds 8-slot ring (slot t+5 issued at step t by
// wave (t+5)&1), counted vmcnt(LPS) at step end. 8-step unroll => static
// addressing. launch_bounds(128,1) => full VGPR budget (no remat).
// ---------------------------------------------------------------------------

typedef float float4v __attribute__((ext_vector_type(4)));
typedef float float2v __attribute__((ext_vector_type(2)));
typedef short short8v __attribute__((ext_vector_type(8)));
typedef unsigned uint2v __attribute__((ext_vector_type(2)));

#define N_SAMPLES 4096
#define T_STEPS 256
#define HSTR 40           // shorts per sample row in H (32 units + pad)
#define HBUF (16 * HSTR)  // shorts per H buffer

#define LGKM0 asm volatile("s_waitcnt lgkmcnt(0)" ::: "memory")

__device__ __forceinline__ short bf16r(float f) {
  unsigned u = __float_as_uint(f);
  u += 0x7FFFu + ((u >> 16) & 1u);
  return (short)(u >> 16);
}
__device__ __forceinline__ unsigned cvt_pk_bf16(float lo, float hi) {
  unsigned r;
  asm("v_cvt_pk_bf16_f32 %0, %1, %2" : "=v"(r) : "v"(lo), "v"(hi));
  return r;
}
// sigmoid(x) = 1/(1+2^(-x*log2e)); tanh(x) = 1 - 2/(2^(2x*log2e)+1)
__device__ __forceinline__ float sigm_(float x) {
  return __builtin_amdgcn_rcpf(1.0f +
                               __builtin_amdgcn_exp2f(x * -1.44269504f));
}
__device__ __forceinline__ float tanh_(float x) {
  return 1.0f - 2.0f * __builtin_amdgcn_rcpf(
                           1.0f + __builtin_amdgcn_exp2f(x * 2.88539009f));
}
__device__ __forceinline__ float4v mfma32(short8v a, short8v b, float4v c) {
  return __builtin_amdgcn_mfma_f32_16x16x32_bf16(a, b, c, 0, 0, 0);
}
__device__ __forceinline__ void gld16(const float* g, float* l) {
  __builtin_amdgcn_global_load_lds(
      (const __attribute__((address_space(1))) unsigned int*)g,
      (__attribute__((address_space(3))) unsigned int*)l, 16, 0, 0);
}

// LDS: x ring 8*16*74*4 = 37888 + H 2*640*2 = 2560 + pad => 40512
#define SMEM_BYTES (8 * 16 * 74 * 4 + 2 * HBUF * 2 + 64)

template <int D, int NK32, int LPS>
__device__ void lstm2w(const float* __restrict__ x,
                       const float* __restrict__ Wih,
                       const float* __restrict__ Whh,
                       const float* __restrict__ bih,
                       const float* __restrict__ bhh,
                       const float* __restrict__ Wo,
                       const float* __restrict__ bo,
                       float* __restrict__ outf, int n0, char* smem) {
  constexpr int FPS = 16 * D;    // floats per ring slot
  constexpr int UPS = FPS / 4;   // 16B units per slot
  constexpr int FULL = UPS / 64;
  constexpr int REM = UPS % 64;

  float* xbuf = (float*)smem;                                   // [8][FPS]
  unsigned short* Hu = (unsigned short*)(smem + 8 * FPS * 4);   // [2][16][40]

  const int tid = threadIdx.x;
  const int wid = tid >> 6;   // 0..1
  const int lane = tid & 63;
  const int c = lane & 15;
  const int q = lane >> 4;

  auto stageslot = [&](int t) {
    const float* gs = x + (size_t)t * (N_SAMPLES * D) + (size_t)n0 * D;
    float* ls = xbuf + (t & 7) * FPS;
#pragma unroll
    for (int r = 0; r < FULL; ++r)
      gld16(gs + (r * 64 + lane) * 4, ls + r * 256);
    if (REM) {
      if (lane < REM) gld16(gs + (FULL * 64 + lane) * 4, ls + FULL * 256);
    }
  };

  // prologue staging: wave0 -> slots 0,2,4 ; wave1 -> slots 1,3
  if (wid == 0) { stageslot(0); stageslot(2); stageslot(4); }
  else          { stageslot(1); stageslot(3); }

  // stationary weights: 4 tiles (16 units) per wave; zeros beyond D carry
  // the tail masking for x implicitly.
  short8v wfx[4][NK32], wfh[4];
  float4v binit[4];
#pragma unroll
  for (int T = 0; T < 4; ++T) {
    const int G = (c & 3) * 32 + wid * 16 + (c >> 2) * 4 + T;  // A-row c
    const float* wr = Wih + G * D;
#pragma unroll
    for (int kt = 0; kt < NK32; ++kt) {
      short8v s;
#pragma unroll
      for (int e = 0; e < 8; ++e) {
        const int d = kt * 32 + q * 8 + e;
        s[e] = (d < D) ? bf16r(wr[d]) : (short)0;
      }
      wfx[T][kt] = s;
    }
    const float* hr = Whh + G * 32;
#pragma unroll
    for (int e = 0; e < 8; ++e) wfh[T][e] = bf16r(hr[q * 8 + e]);
#pragma unroll
    for (int r = 0; r < 4; ++r) {
      const int Gr = r * 32 + wid * 16 + q * 4 + T;  // C reg r mapping
      binit[T][r] = bih[Gr] + bhh[Gr];
    }
  }

  // zero both H buffers
  {
    unsigned* Hz = (unsigned*)Hu;
    for (int i = tid; i < 640; i += 128) Hz[i] = 0;
  }

  // prologue waits: wave0 ensure slot0, wave1 ensure slot1
  if (wid == 0) {
    if constexpr (LPS == 5) asm volatile("s_waitcnt vmcnt(10)" ::: "memory");
    else                    asm volatile("s_waitcnt vmcnt(6)" ::: "memory");
  } else {
    if constexpr (LPS == 5) asm volatile("s_waitcnt vmcnt(5)" ::: "memory");
    else                    asm volatile("s_waitcnt vmcnt(3)" ::: "memory");
  }
  LGKM0;
  __builtin_amdgcn_s_barrier();

  auto ldcvt = [&](const float* xs0, short8v* xo) {
    const float* xs = xs0 + c * D;
#pragma unroll
    for (int kt = 0; kt < NK32; ++kt) {
      const float* p = xs + kt * 32 + q * 8;
      const float2v r0 = *(const float2v*)(p);
      const float2v r1 = *(const float2v*)(p + 2);
      const float2v r2 = *(const float2v*)(p + 4);
      const float2v r3 = *(const float2v*)(p + 6);
      union { short8v s; unsigned u[4]; } fr;
      fr.u[0] = cvt_pk_bf16(r0[0], r0[1]);
      fr.u[1] = cvt_pk_bf16(r1[0], r1[1]);
      fr.u[2] = cvt_pk_bf16(r2[0], r2[1]);
      fr.u[3] = cvt_pk_bf16(r3[0], r3[1]);
      xo[kt] = fr.s;
    }
  };

  float cst[4] = {0.0f, 0.0f, 0.0f, 0.0f};
  float4v gxA[4], gxB[4];
  {
    short8v xF[NK32];
    ldcvt(xbuf, xF);  // slot 0 = x[0]
#pragma unroll
    for (int T = 0; T < 4; ++T) {
      float4v g4 = binit[T];
#pragma unroll
      for (int kt = 0; kt < NK32; ++kt) g4 = mfma32(wfx[T][kt], xF[kt], g4);
      gxA[T] = g4;
    }
  }

  // one step; i = t&7 compile-time, gc = gates for t, gn -> gates for t+1
  auto STEP = [&](int t, int i, float4v (&gc)[4], float4v (&gn)[4]) {
    const int pb = i & 1;
    // on-chain: h of step t-1 (all 32 units)
    const short8v hB = *(const short8v*)(Hu + pb * HBUF + c * HSTR + q * 8);
    // staging (alternating waves), slot (i+5)&7
    if (((i + 5) & 1) == wid && t + 5 < T_STEPS) stageslot(t + 5);
    // off-chain: x[t+1] frags + production
    short8v xN[NK32];
    ldcvt(xbuf + ((i + 1) & 7) * FPS, xN);
#pragma unroll
    for (int T = 0; T < 4; ++T) {
      float4v g4 = binit[T];
#pragma unroll
      for (int kt = 0; kt < NK32; ++kt) g4 = mfma32(wfx[T][kt], xN[kt], g4);
      gn[T] = g4;
    }
    // on-chain: 4 h-MFMAs + lean trans (prioritized)
    __builtin_amdgcn_s_setprio(1);
    float hv[4];
#pragma unroll
    for (int T = 0; T < 4; ++T) {
      const float4v acc = mfma32(wfh[T], hB, gc[T]);
      const float iv = sigm_(acc[0]);
      const float fv = sigm_(acc[1]);
      const float gv = tanh_(acc[2]);
      const float ov = sigm_(acc[3]);
      const float cv = fv * cst[T] + iv * gv;
      cst[T] = cv;
      hv[T] = ov * tanh_(cv);
    }
    uint2v hp;
    hp[0] = cvt_pk_bf16(hv[0], hv[1]);
    hp[1] = cvt_pk_bf16(hv[2], hv[3]);
    *(uint2v*)(Hu + (1 - pb) * HBUF + c * HSTR + wid * 16 + q * 4) = hp;
    __builtin_amdgcn_s_setprio(0);
    LGKM0;  // h write (and ds reads) drained
    if constexpr (LPS == 5) asm volatile("s_waitcnt vmcnt(5)" ::: "memory");
    else                    asm volatile("s_waitcnt vmcnt(3)" ::: "memory");
    __builtin_amdgcn_s_barrier();
  };

  for (int tb = 0; tb < T_STEPS; tb += 8) {
    STEP(tb + 0, 0, gxA, gxB);
    STEP(tb + 1, 1, gxB, gxA);
    STEP(tb + 2, 2, gxA, gxB);
    STEP(tb + 3, 3, gxB, gxA);
    STEP(tb + 4, 4, gxA, gxB);
    STEP(tb + 5, 5, gxB, gxA);
    STEP(tb + 6, 6, gxA, gxB);
    STEP(tb + 7, 7, gxB, gxA);
  }

  // epilogue: h[255] in H buffer 0 (t=255 odd writes pb^1=0)
  {
    const short8v hB = *(const short8v*)(Hu + c * HSTR + q * 8);
    const float* wor = Wo + (16 * wid + c) * 32;
    short8v w8;
#pragma unroll
    for (int e = 0; e < 8; ++e) w8[e] = bf16r(wor[q * 8 + e]);
    float4v o4 = {0.0f, 0.0f, 0.0f, 0.0f};
    o4 = mfma32(w8, hB, o4);
    float4v res;
#pragma unroll
    for (int r = 0; r < 4; ++r)
      res[r] = fmaxf(o4[r] + bo[16 * wid + q * 4 + r], 0.0f);
    *(float4v*)(outf + (size_t)(n0 + c) * 32 + 16 * wid + q * 4) = res;
  }
}

__global__ __launch_bounds__(128, 1) void lstm_both(
    const float* __restrict__ a, const float* __restrict__ v,
    const float* __restrict__ aWih, const float* __restrict__ aWhh,
    const float* __restrict__ abih, const float* __restrict__ abhh,
    const float* __restrict__ aWo, const float* __restrict__ abo,
    const float* __restrict__ vWih, const float* __restrict__ vWhh,
    const float* __restrict__ vbih, const float* __restrict__ vbhh,
    const float* __restrict__ vWo, const float* __restrict__ vbo,
    float* __restrict__ afw, float* __restrict__ vfw) {
  __shared__ __align__(16) char smem[SMEM_BYTES];
  const int b = blockIdx.x;
  if (b < 256)
    lstm2w<74, 3, 5>(a, aWih, aWhh, abih, abhh, aWo, abo, afw, b * 16, smem);
  else
    lstm2w<47, 2, 3>(v, vWih, vWhh, vbih, vbhh, vWo, vbo, vfw,
                     (b - 256) * 16, smem);
}

// ---------------------------------------------------------------------------
// lf = relu(relu(l @ lW1^T + lb1) @ lW2^T + lb2)   [4096,768]->[4096,32]
// ---------------------------------------------------------------------------
__global__ __launch_bounds__(256) void lf_kernel(
    const float* __restrict__ l, const float* __restrict__ lW1,
    const float* __restrict__ lb1, const float* __restrict__ lW2,
    const float* __restrict__ lb2, float* __restrict__ lf) {
  __shared__ __align__(16) float lsh[16 * 768];
  __shared__ __align__(16) float h1sh[16 * 128];
  const int tid = threadIdx.x;
  const int n0 = blockIdx.x * 16;

  {
    const float4v* src = (const float4v*)(l + (size_t)n0 * 768);
    float4v* dst = (float4v*)lsh;
#pragma unroll
    for (int i = 0; i < 12; ++i) dst[tid + i * 256] = src[tid + i * 256];
  }
  __syncthreads();

  {
    const int u = tid & 127;
    const int sg = tid >> 7;
    float acc[8];
#pragma unroll
    for (int i = 0; i < 8; ++i) acc[i] = 0.0f;
    const float4v* wrow = (const float4v*)(lW1 + u * 768);
    for (int k4 = 0; k4 < 192; ++k4) {
      const float4v w = wrow[k4];
#pragma unroll
      for (int i = 0; i < 8; ++i) {
        const float4v xv = ((const float4v*)(lsh + (sg * 8 + i) * 768))[k4];
        acc[i] += w[0] * xv[0] + w[1] * xv[1] + w[2] * xv[2] + w[3] * xv[3];
      }
    }
    const float b = lb1[u];
#pragma unroll
    for (int i = 0; i < 8; ++i)
      h1sh[(sg * 8 + i) * 128 + u] = fmaxf(acc[i] + b, 0.0f);
  }
  __syncthreads();

  {
    const int u2 = tid & 31;
    const int sg2 = tid >> 5;
    float acc0 = 0.0f, acc1 = 0.0f;
    const float4v* w2 = (const float4v*)(lW2 + u2 * 128);
#pragma unroll
    for (int k4 = 0; k4 < 32; ++k4) {
      const float4v w = w2[k4];
      const float4v xa = ((const float4v*)(h1sh + sg2 * 128))[k4];
      const float4v xb = ((const float4v*)(h1sh + (sg2 + 8) * 128))[k4];
      acc0 += w[0] * xa[0] + w[1] * xa[1] + w[2] * xa[2] + w[3] * xa[3];
      acc1 += w[0] * xb[0] + w[1] * xb[1] + w[2] * xb[2] + w[3] * xb[3];
    }
    const float b2 = lb2[u2];
    lf[(size_t)(n0 + sg2) * 32 + u2] = fmaxf(acc0 + b2, 0.0f);
    lf[(size_t)(n0 + sg2 + 8) * 32 + u2] = fmaxf(acc1 + b2, 0.0f);
  }
}

// ---------------------------------------------------------------------------
// Transformer block + post-fusion head. 32 lanes/sample, 8 samples/block.
// ---------------------------------------------------------------------------
__global__ __launch_bounds__(256) void head_kernel(
    const float* __restrict__ lf, const float* __restrict__ af,
    const float* __restrict__ vf, const float* __restrict__ Wq,
    const float* __restrict__ bq, const float* __restrict__ Wk,
    const float* __restrict__ bk, const float* __restrict__ Wv,
    const float* __restrict__ bv, const float* __restrict__ Wz,
    const float* __restrict__ bz, const float* __restrict__ Wff,
    const float* __restrict__ bff, const float* __restrict__ g1,
    const float* __restrict__ be1, const float* __restrict__ g2,
    const float* __restrict__ be2, const float* __restrict__ Wp1,
    const float* __restrict__ bp1, const float* __restrict__ Wp2,
    const float* __restrict__ bp2, float* __restrict__ out) {
  __shared__ float shA[8][3][33];
  __shared__ float shB[8][3][33];
  const int tid = threadIdx.x;
  const int j = tid & 31;
  const int slot = tid >> 5;
  const int n = blockIdx.x * 8 + slot;
  const size_t off = (size_t)n * 32 + j;

  const float x0 = lf[off], x1 = af[off], x2 = vf[off];

  auto ln3 = [&](float a0, float a1, float a2, const float* g,
                 const float* be, float* o) {
    float s = a0 + a1 + a2;
    s += __shfl_xor(s, 1); s += __shfl_xor(s, 2); s += __shfl_xor(s, 4);
    s += __shfl_xor(s, 8); s += __shfl_xor(s, 16);
    const float mu = s * (1.0f / 96.0f);
    const float d0 = a0 - mu, d1 = a1 - mu, d2 = a2 - mu;
    float ss = d0 * d0 + d1 * d1 + d2 * d2;
    ss += __shfl_xor(ss, 1); ss += __shfl_xor(ss, 2); ss += __shfl_xor(ss, 4);
    ss += __shfl_xor(ss, 8); ss += __shfl_xor(ss, 16);
    const float rs = rsqrtf(ss * (1.0f / 96.0f) + 1e-5f);
    o[0] = d0 * rs * g[j] + be[j];
    o[1] = d1 * rs * g[32 + j] + be[32 + j];
    o[2] = d2 * rs * g[64 + j] + be[64 + j];
  };

  float z[3];
  ln3(x0, x1, x2, g1, be1, z);
  shA[slot][0][j] = z[0]; shA[slot][1][j] = z[1]; shA[slot][2][j] = z[2];
  __syncthreads();

  float qv[3], kv[3], vv[3];
  {
    const float bqj = bq[j], bkj = bk[j], bvj = bv[j];
    qv[0] = bqj; qv[1] = bqj; qv[2] = bqj;
    kv[0] = bkj; kv[1] = bkj; kv[2] = bkj;
    vv[0] = bvj; vv[1] = bvj; vv[2] = bvj;
    const float* wqr = Wq + j * 32;
    const float* wkr = Wk + j * 32;
    const float* wvr = Wv + j * 32;
#pragma unroll 8
    for (int k = 0; k < 32; ++k) {
      const float zz0 = shA[slot][0][k], zz1 = shA[slot][1][k],
                  zz2 = shA[slot][2][k];
      const float wq = wqr[k], wk_ = wkr[k], wv_ = wvr[k];
      qv[0] += wq * zz0;  qv[1] += wq * zz1;  qv[2] += wq * zz2;
      kv[0] += wk_ * zz0; kv[1] += wk_ * zz1; kv[2] += wk_ * zz2;
      vv[0] += wv_ * zz0; vv[1] += wv_ * zz1; vv[2] += wv_ * zz2;
    }
  }

  float at[3][3];
#pragma unroll
  for (int s = 0; s < 3; ++s)
#pragma unroll
    for (int t2 = 0; t2 < 3; ++t2) {
      float p = qv[s] * kv[t2];
      p += __shfl_xor(p, 1); p += __shfl_xor(p, 2); p += __shfl_xor(p, 4);
      at[s][t2] = p;
    }
#pragma unroll
  for (int s = 0; s < 3; ++s) {
    const float m = fmaxf(fmaxf(at[s][0], at[s][1]), at[s][2]);
    const float e0 = __expf(at[s][0] - m), e1 = __expf(at[s][1] - m),
                e2 = __expf(at[s][2] - m);
    const float sc = 0.35355339059327373f * __fdividef(1.0f, e0 + e1 + e2);
    at[s][0] = e0 * sc; at[s][1] = e1 * sc; at[s][2] = e2 * sc;
  }
  float zc[3];
#pragma unroll
  for (int s = 0; s < 3; ++s)
    zc[s] = at[s][0] * vv[0] + at[s][1] * vv[1] + at[s][2] * vv[2];
  shB[slot][0][j] = zc[0]; shB[slot][1][j] = zc[1]; shB[slot][2][j] = zc[2];
  __syncthreads();

  const float bzj = bz[j];
  float z2a[3] = {bzj + x0, bzj + x1, bzj + x2};
  {
    const float* wzr = Wz + j * 32;
#pragma unroll 8
    for (int k = 0; k < 32; ++k) {
      const float w = wzr[k];
      z2a[0] += w * shB[slot][0][k];
      z2a[1] += w * shB[slot][1][k];
      z2a[2] += w * shB[slot][2][k];
    }
  }

  float zn[3];
  ln3(z2a[0], z2a[1], z2a[2], g2, be2, zn);
  shA[slot][0][j] = zn[0]; shA[slot][1][j] = zn[1]; shA[slot][2][j] = zn[2];
  __syncthreads();

  const float bffj = bff[j];
  float Za[3] = {bffj + z2a[0], bffj + z2a[1], bffj + z2a[2]};
  {
    const float* wfr = Wff + j * 32;
#pragma unroll 8
    for (int k = 0; k < 32; ++k) {
      const float w = wfr[k];
      Za[0] += w * shA[slot][0][k];
      Za[1] += w * shA[slot][1][k];
      Za[2] += w * shA[slot][2][k];
    }
  }
  shB[slot][0][j] = Za[0]; shB[slot][1][j] = Za[1]; shB[slot][2][j] = Za[2];
  __syncthreads();

  float p = bp1[j];
  {
    const float* wpr = Wp1 + j * 96;
#pragma unroll
    for (int s = 0; s < 3; ++s)
#pragma unroll 8
      for (int k = 0; k < 32; ++k) p += wpr[s * 32 + k] * shB[slot][s][k];
  }
  p = fmaxf(p, 0.0f);
  float l0 = Wp2[j] * p, l1 = Wp2[32 + j] * p;
  l0 += __shfl_xor(l0, 1); l0 += __shfl_xor(l0, 2); l0 += __shfl_xor(l0, 4);
  l0 += __shfl_xor(l0, 8); l0 += __shfl_xor(l0, 16);
  l1 += __shfl_xor(l1, 1); l1 += __shfl_xor(l1, 2); l1 += __shfl_xor(l1, 4);
  l1 += __shfl_xor(l1, 8); l1 += __shfl_xor(l1, 16);
  l0 += bp2[0]; l1 += bp2[1];
  const float mx = fmaxf(l0, l1);
  const float e0 = __expf(l0 - mx), e1 = __expf(l1 - mx);
  const float inv = __fdividef(1.0f, e0 + e1);
  if (j == 0) {
    out[(size_t)n * 2 + 0] = e0 * inv;
    out[(size_t)n * 2 + 1] = e1 * inv;
  }
}

// ---------------------------------------------------------------------------
extern "C" void kernel_launch(void* const* d_in, const int* in_sizes, int n_in,
                              void* d_out, int out_size, void* d_ws,
                              size_t ws_size, hipStream_t stream) {
  const float* l    = (const float*)d_in[0];
  const float* a    = (const float*)d_in[1];
  const float* v    = (const float*)d_in[2];
  const float* lW1  = (const float*)d_in[3];
  const float* lb1  = (const float*)d_in[4];
  const float* lW2  = (const float*)d_in[5];
  const float* lb2  = (const float*)d_in[6];
  const float* aWih = (const float*)d_in[7];
  const float* aWhh = (const float*)d_in[8];
  const float* abih = (const float*)d_in[9];
  const float* abhh = (const float*)d_in[10];
  const float* aWo  = (const float*)d_in[11];
  const float* abo  = (const float*)d_in[12];
  const float* vWih = (const float*)d_in[13];
  const float* vWhh = (const float*)d_in[14];
  const float* vbih = (const float*)d_in[15];
  const float* vbhh = (const float*)d_in[16];
  const float* vWo  = (const float*)d_in[17];
  const float* vbo  = (const float*)d_in[18];
  const float* Wq   = (const float*)d_in[19];
  const float* bq   = (const float*)d_in[20];
  const float* Wk   = (const float*)d_in[21];
  const float* bk   = (const float*)d_in[22];
  const float* Wv   = (const float*)d_in[23];
  const float* bv   = (const float*)d_in[24];
  const float* Wz   = (const float*)d_in[25];
  const float* bz   = (const float*)d_in[26];
  const float* Wff  = (const float*)d_in[27];
  const float* bff  = (const float*)d_in[28];
  const float* g1   = (const float*)d_in[29];
  const float* be1  = (const float*)d_in[30];
  const float* g2   = (const float*)d_in[31];
  const float* be2  = (const float*)d_in[32];
  const float* Wp1  = (const float*)d_in[33];
  const float* bp1  = (const float*)d_in[34];
  const float* Wp2  = (const float*)d_in[35];
  const float* bp2  = (const float*)d_in[36];

  float* out = (float*)d_out;
  float* ws = (float*)d_ws;
  float* lfw = ws;
  float* afw = ws + 4096 * 32;
  float* vfw = ws + 2 * 4096 * 32;

  hipLaunchKernelGGL(lstm_both, dim3(512), dim3(128), 0, stream, a, v, aWih,
                     aWhh, abih, abhh, aWo, abo, vWih, vWhh, vbih, vbhh, vWo,
                     vbo, afw, vfw);
  hipLaunchKernelGGL(lf_kernel, dim3(256), dim3(256), 0, stream, l, lW1, lb1,
                     lW2, lb2, lfw);
  hipLaunchKernelGGL(head_kernel, dim3(512), dim3(256), 0, stream, lfw, afw,
                     vfw, Wq, bq, Wk, bk, Wv, bv, Wz, bz, Wff, bff, g1, be1,
                     g2, be2, Wp1, bp1, Wp2, bp2, out);
}

// Round 9
// 272.268 us; speedup vs baseline: 2.3983x; 1.1406x over previous
//
#include <hip/hip_runtime.h>

// ---------------------------------------------------------------------------
// Fused multimodal net: l-MLP + 2 LSTMs (MFMA bf16) + tiny transformer head.
// N=4096, T=256, DA=74, DV=47, hidden=32.
//
// LSTM: producer/consumer wave specialization. Block = 256 threads = 4 waves
// per 16-sample group (512 groups). Waves 2,3 (producers, half p=wid-2):
// compute gx[t] = bias + Wih@x[t] three steps ahead (no h dependency),
// x staged via global_load_lds 8-slot ring (counted vmcnt, never 0), gx
// written to a 4-slot LDS ring. Waves 0,1 (consumers, half wid): per step
// 4 b128 gx-reads + 1 b128 h-read -> 4 h-MFMAs -> lean trans -> b64 h-write
// -> block barrier. Separate instruction streams => producer HBM/latency
// waits never stall the consumer chain; the step is HBM/chain-paced.
// Row map (r8-verified): gate row G = r*32 + half*16 + q*4 + T; lane (q,c)
// C-regs 0..3 = i,f,g,o of unit half*16+q*4+T.
// lf MLP fused into a-blocks' epilogue (LDS reused after the main loop).
// ---------------------------------------------------------------------------

typedef float float4v __attribute__((ext_vector_type(4)));
typedef float float2v __attribute__((ext_vector_type(2)));
typedef short short8v __attribute__((ext_vector_type(8)));
typedef unsigned uint2v __attribute__((ext_vector_type(2)));

#define N_SAMPLES 4096
#define T_STEPS 256
#define HSTR 40           // shorts per sample row in H (32 units + pad)
#define HBUF (16 * HSTR)  // shorts per H buffer
#define GXBYTES 32768     // 4 slots x 2 halves x 4 tiles x 64 lanes x 16B

#define LGKM0 asm volatile("s_waitcnt lgkmcnt(0)" ::: "memory")

__device__ __forceinline__ short bf16r(float f) {
  unsigned u = __float_as_uint(f);
  u += 0x7FFFu + ((u >> 16) & 1u);
  return (short)(u >> 16);
}
__device__ __forceinline__ unsigned cvt_pk_bf16(float lo, float hi) {
  unsigned r;
  asm("v_cvt_pk_bf16_f32 %0, %1, %2" : "=v"(r) : "v"(lo), "v"(hi));
  return r;
}
__device__ __forceinline__ float sigm_(float x) {
  return __builtin_amdgcn_rcpf(1.0f +
                               __builtin_amdgcn_exp2f(x * -1.44269504f));
}
__device__ __forceinline__ float tanh_(float x) {
  return 1.0f - 2.0f * __builtin_amdgcn_rcpf(
                           1.0f + __builtin_amdgcn_exp2f(x * 2.88539009f));
}
__device__ __forceinline__ float4v mfma32(short8v a, short8v b, float4v c) {
  return __builtin_amdgcn_mfma_f32_16x16x32_bf16(a, b, c, 0, 0, 0);
}
__device__ __forceinline__ void gld16(const float* g, float* l) {
  __builtin_amdgcn_global_load_lds(
      (const __attribute__((address_space(1))) unsigned int*)g,
      (__attribute__((address_space(3))) unsigned int*)l, 16, 0, 0);
}

// LDS: x ring 8*16*74*4 = 37888 + gx 32768 + H 2560 + pad = 73280
#define SMEM_BYTES (8 * 16 * 74 * 4 + GXBYTES + 2 * HBUF * 2 + 64)

template <int D, int NK32, int LPS>
__device__ void lstm_pc(const float* __restrict__ x,
                        const float* __restrict__ Wih,
                        const float* __restrict__ Whh,
                        const float* __restrict__ bih,
                        const float* __restrict__ bhh,
                        const float* __restrict__ Wo,
                        const float* __restrict__ bo,
                        float* __restrict__ outf, int n0, char* smem) {
  constexpr int FPS = 16 * D;    // floats per x ring slot
  constexpr int UPS = FPS / 4;   // 16B units per slot
  constexpr int FULL = UPS / 64;
  constexpr int REM = UPS % 64;

  float* xbuf = (float*)smem;                              // [8][FPS]
  float* gxb = (float*)(smem + 8 * FPS * 4);               // gx ring
  unsigned short* Hu =
      (unsigned short*)(smem + 8 * FPS * 4 + GXBYTES);     // [2][16][40]

  const int tid = threadIdx.x;
  const int wid = tid >> 6;   // 0,1 consumers; 2,3 producers
  const int lane = tid & 63;
  const int c = lane & 15;
  const int q = lane >> 4;

  auto stageslot = [&](int t) {
    const float* gs = x + (size_t)t * (N_SAMPLES * D) + (size_t)n0 * D;
    float* ls = xbuf + (t & 7) * FPS;
#pragma unroll
    for (int r = 0; r < FULL; ++r)
      gld16(gs + (r * 64 + lane) * 4, ls + r * 256);
    if (REM) {
      if (lane < REM) gld16(gs + (FULL * 64 + lane) * 4, ls + FULL * 256);
    }
  };

  auto ldcvt = [&](const float* xs0, short8v* xo) {
    const float* xs = xs0 + c * D;
#pragma unroll
    for (int kt = 0; kt < NK32; ++kt) {
      const float* pp = xs + kt * 32 + q * 8;
      const float2v r0 = *(const float2v*)(pp);
      const float2v r1 = *(const float2v*)(pp + 2);
      const float2v r2 = *(const float2v*)(pp + 4);
      const float2v r3 = *(const float2v*)(pp + 6);
      union { short8v s; unsigned u[4]; } fr;
      fr.u[0] = cvt_pk_bf16(r0[0], r0[1]);
      fr.u[1] = cvt_pk_bf16(r1[0], r1[1]);
      fr.u[2] = cvt_pk_bf16(r2[0], r2[1]);
      fr.u[3] = cvt_pk_bf16(r3[0], r3[1]);
      xo[kt] = fr.s;
    }
  };

  if (wid >= 2) {
    // ---------------- PRODUCER (half p): gx[t] = bias + Wih@x[t] ----------
    const int p = wid - 2;
    // prologue staging: P0 -> slots 0,2,4 ; P1 -> slots 1,3,5
#pragma unroll
    for (int s = 0; s < 6; ++s)
      if ((s & 1) == p) stageslot(s);

    // stationary weights (overlaps staging HBM latency)
    short8v wfx[4][NK32];
    float4v binit[4];
#pragma unroll
    for (int T = 0; T < 4; ++T) {
      const int G = (c & 3) * 32 + p * 16 + (c >> 2) * 4 + T;
      const float* wr = Wih + G * D;
#pragma unroll
      for (int kt = 0; kt < NK32; ++kt) {
        short8v s8;
#pragma unroll
        for (int e = 0; e < 8; ++e) {
          const int d = kt * 32 + q * 8 + e;
          s8[e] = (d < D) ? bf16r(wr[d]) : (short)0;
        }
        wfx[T][kt] = s8;
      }
#pragma unroll
      for (int r = 0; r < 4; ++r) {
        const int Gr = r * 32 + p * 16 + q * 4 + T;
        binit[T][r] = bih[Gr] + bhh[Gr];
      }
    }
    asm volatile("s_waitcnt vmcnt(0)" ::: "memory");
    __builtin_amdgcn_s_barrier();  // #1: x slots 0..5 visible to both producers

    // produce gx[0..2]
#pragma unroll
    for (int kk = 0; kk < 3; ++kk) {
      short8v xN[NK32];
      ldcvt(xbuf + kk * FPS, xN);
#pragma unroll
      for (int T = 0; T < 4; ++T) {
        float4v g4 = binit[T];
#pragma unroll
        for (int kt = 0; kt < NK32; ++kt) g4 = mfma32(wfx[T][kt], xN[kt], g4);
        *(float4v*)(gxb + ((kk * 2 + p) * 4 + T) * 256 + lane * 4) = g4;
      }
    }
    LGKM0;
    __builtin_amdgcn_s_barrier();  // #2: gx[0..2] visible

    for (int kb = 0; kb < T_STEPS; kb += 8) {
#pragma unroll
      for (int i = 0; i < 8; ++i) {
        const int k = kb + i;
        if (k <= T_STEPS - 4) {  // produce gx[k+3]
          short8v xN[NK32];
          ldcvt(xbuf + ((i + 3) & 7) * FPS, xN);
#pragma unroll
          for (int T = 0; T < 4; ++T) {
            float4v g4 = binit[T];
#pragma unroll
            for (int kt = 0; kt < NK32; ++kt)
              g4 = mfma32(wfx[T][kt], xN[kt], g4);
            *(float4v*)(gxb + ((((i + 3) & 3) * 2 + p) * 4 + T) * 256 +
                        lane * 4) = g4;
          }
        }
        if (((i + 6) & 1) == p && k <= T_STEPS - 7) stageslot(k + 6);
        LGKM0;  // gx writes drained before barrier
        if constexpr (LPS == 5)
          asm volatile("s_waitcnt vmcnt(5)" ::: "memory");
        else
          asm volatile("s_waitcnt vmcnt(3)" ::: "memory");
        __builtin_amdgcn_s_barrier();
      }
    }
  } else {
    // ---------------- CONSUMER (half wid): h recurrence -------------------
    short8v wfh[4];
#pragma unroll
    for (int T = 0; T < 4; ++T) {
      const int G = (c & 3) * 32 + wid * 16 + (c >> 2) * 4 + T;
      const float* hr = Whh + G * 32;
#pragma unroll
      for (int e = 0; e < 8; ++e) wfh[T][e] = bf16r(hr[q * 8 + e]);
    }
    {  // zero both H buffers (640 dwords over 128 consumer threads)
      unsigned* Hz = (unsigned*)Hu;
      for (int idx = tid; idx < 640; idx += 128) Hz[idx] = 0;
    }
    LGKM0;
    __builtin_amdgcn_s_barrier();  // #1
    __builtin_amdgcn_s_barrier();  // #2 (producers filled gx[0..2])

    float cst[4] = {0.0f, 0.0f, 0.0f, 0.0f};
    for (int kb = 0; kb < T_STEPS; kb += 8) {
#pragma unroll
      for (int i = 0; i < 8; ++i) {
        const int pb = i & 1;
        float4v gxv[4];
#pragma unroll
        for (int T = 0; T < 4; ++T)
          gxv[T] = *(const float4v*)(gxb + (((i & 3) * 2 + wid) * 4 + T) *
                                              256 + lane * 4);
        const short8v hB =
            *(const short8v*)(Hu + pb * HBUF + c * HSTR + q * 8);
        __builtin_amdgcn_s_setprio(1);
        float hv[4];
#pragma unroll
        for (int T = 0; T < 4; ++T) {
          const float4v acc = mfma32(wfh[T], hB, gxv[T]);
          const float iv = sigm_(acc[0]);
          const float fv = sigm_(acc[1]);
          const float gv = tanh_(acc[2]);
          const float ov = sigm_(acc[3]);
          const float cv = fv * cst[T] + iv * gv;
          cst[T] = cv;
          hv[T] = ov * tanh_(cv);
        }
        uint2v hp;
        hp[0] = cvt_pk_bf16(hv[0], hv[1]);
        hp[1] = cvt_pk_bf16(hv[2], hv[3]);
        *(uint2v*)(Hu + (1 - pb) * HBUF + c * HSTR + wid * 16 + q * 4) = hp;
        __builtin_amdgcn_s_setprio(0);
        LGKM0;  // h write visible
        __builtin_amdgcn_s_barrier();
      }
    }

    // epilogue: h[255] in H buffer 0; out = relu(h @ Wo^T + bo)
    {
      const short8v hB = *(const short8v*)(Hu + c * HSTR + q * 8);
      const float* wor = Wo + (16 * wid + c) * 32;
      short8v w8;
#pragma unroll
      for (int e = 0; e < 8; ++e) w8[e] = bf16r(wor[q * 8 + e]);
      float4v o4 = {0.0f, 0.0f, 0.0f, 0.0f};
      o4 = mfma32(w8, hB, o4);
      float4v res;
#pragma unroll
      for (int r = 0; r < 4; ++r)
        res[r] = fmaxf(o4[r] + bo[16 * wid + q * 4 + r], 0.0f);
      *(float4v*)(outf + (size_t)(n0 + c) * 32 + 16 * wid + q * 4) = res;
    }
  }
}

__global__ __launch_bounds__(256, 1) void lstm_both(
    const float* __restrict__ a, const float* __restrict__ v,
    const float* __restrict__ aWih, const float* __restrict__ aWhh,
    const float* __restrict__ abih, const float* __restrict__ abhh,
    const float* __restrict__ aWo, const float* __restrict__ abo,
    const float* __restrict__ vWih, const float* __restrict__ vWhh,
    const float* __restrict__ vbih, const float* __restrict__ vbhh,
    const float* __restrict__ vWo, const float* __restrict__ vbo,
    const float* __restrict__ l, const float* __restrict__ lW1,
    const float* __restrict__ lb1, const float* __restrict__ lW2,
    const float* __restrict__ lb2, float* __restrict__ lfw,
    float* __restrict__ afw, float* __restrict__ vfw) {
  __shared__ __align__(16) char smem[SMEM_BYTES];
  const int b = blockIdx.x;
  if (b < 256) {
    lstm_pc<74, 3, 5>(a, aWih, aWhh, abih, abhh, aWo, abo, afw, b * 16, smem);

    // ---- fused lf MLP for this block's 16 samples (LDS reused) ----
    __syncthreads();
    float* lsh = (float*)smem;               // 16*768 floats = 49152 B
    float* h1sh = (float*)(smem + 49152);    // 16*128 floats = 8192 B
    const int tid = threadIdx.x;
    const int n0 = b * 16;
    {
      const float4v* src = (const float4v*)(l + (size_t)n0 * 768);
      float4v* dst = (float4v*)lsh;
#pragma unroll
      for (int i = 0; i < 12; ++i) dst[tid + i * 256] = src[tid + i * 256];
    }
    __syncthreads();
    {
      const int u = tid & 127;
      const int sg = tid >> 7;
      float acc[8];
#pragma unroll
      for (int i = 0; i < 8; ++i) acc[i] = 0.0f;
      const float4v* wrow = (const float4v*)(lW1 + u * 768);
      for (int k4 = 0; k4 < 192; ++k4) {
        const float4v w = wrow[k4];
#pragma unroll
        for (int i = 0; i < 8; ++i) {
          const float4v xv = ((const float4v*)(lsh + (sg * 8 + i) * 768))[k4];
          acc[i] += w[0] * xv[0] + w[1] * xv[1] + w[2] * xv[2] + w[3] * xv[3];
        }
      }
      const float bb = lb1[u];
#pragma unroll
      for (int i = 0; i < 8; ++i)
        h1sh[(sg * 8 + i) * 128 + u] = fmaxf(acc[i] + bb, 0.0f);
    }
    __syncthreads();
    {
      const int u2 = tid & 31;
      const int sg2 = tid >> 5;
      float acc0 = 0.0f, acc1 = 0.0f;
      const float4v* w2 = (const float4v*)(lW2 + u2 * 128);
#pragma unroll
      for (int k4 = 0; k4 < 32; ++k4) {
        const float4v w = w2[k4];
        const float4v xa = ((const float4v*)(h1sh + sg2 * 128))[k4];
        const float4v xb = ((const float4v*)(h1sh + (sg2 + 8) * 128))[k4];
        acc0 += w[0] * xa[0] + w[1] * xa[1] + w[2] * xa[2] + w[3] * xa[3];
        acc1 += w[0] * xb[0] + w[1] * xb[1] + w[2] * xb[2] + w[3] * xb[3];
      }
      const float b2 = lb2[u2];
      lfw[(size_t)(n0 + sg2) * 32 + u2] = fmaxf(acc0 + b2, 0.0f);
      lfw[(size_t)(n0 + sg2 + 8) * 32 + u2] = fmaxf(acc1 + b2, 0.0f);
    }
  } else {
    lstm_pc<47, 2, 3>(v, vWih, vWhh, vbih, vbhh, vWo, vbo, vfw,
                      (b - 256) * 16, smem);
  }
}

// ---------------------------------------------------------------------------
// Transformer block + post-fusion head. 32 lanes/sample, 8 samples/block.
// ---------------------------------------------------------------------------
__global__ __launch_bounds__(256) void head_kernel(
    const float* __restrict__ lf, const float* __restrict__ af,
    const float* __restrict__ vf, const float* __restrict__ Wq,
    const float* __restrict__ bq, const float* __restrict__ Wk,
    const float* __restrict__ bk, const float* __restrict__ Wv,
    const float* __restrict__ bv, const float* __restrict__ Wz,
    const float* __restrict__ bz, const float* __restrict__ Wff,
    const float* __restrict__ bff, const float* __restrict__ g1,
    const float* __restrict__ be1, const float* __restrict__ g2,
    const float* __restrict__ be2, const float* __restrict__ Wp1,
    const float* __restrict__ bp1, const float* __restrict__ Wp2,
    const float* __restrict__ bp2, float* __restrict__ out) {
  __shared__ float shA[8][3][33];
  __shared__ float shB[8][3][33];
  const int tid = threadIdx.x;
  const int j = tid & 31;
  const int slot = tid >> 5;
  const int n = blockIdx.x * 8 + slot;
  const size_t off = (size_t)n * 32 + j;

  const float x0 = lf[off], x1 = af[off], x2 = vf[off];

  auto ln3 = [&](float a0, float a1, float a2, const float* g,
                 const float* be, float* o) {
    float s = a0 + a1 + a2;
    s += __shfl_xor(s, 1); s += __shfl_xor(s, 2); s += __shfl_xor(s, 4);
    s += __shfl_xor(s, 8); s += __shfl_xor(s, 16);
    const float mu = s * (1.0f / 96.0f);
    const float d0 = a0 - mu, d1 = a1 - mu, d2 = a2 - mu;
    float ss = d0 * d0 + d1 * d1 + d2 * d2;
    ss += __shfl_xor(ss, 1); ss += __shfl_xor(ss, 2); ss += __shfl_xor(ss, 4);
    ss += __shfl_xor(ss, 8); ss += __shfl_xor(ss, 16);
    const float rs = rsqrtf(ss * (1.0f / 96.0f) + 1e-5f);
    o[0] = d0 * rs * g[j] + be[j];
    o[1] = d1 * rs * g[32 + j] + be[32 + j];
    o[2] = d2 * rs * g[64 + j] + be[64 + j];
  };

  float z[3];
  ln3(x0, x1, x2, g1, be1, z);
  shA[slot][0][j] = z[0]; shA[slot][1][j] = z[1]; shA[slot][2][j] = z[2];
  __syncthreads();

  float qv[3], kv[3], vv[3];
  {
    const float bqj = bq[j], bkj = bk[j], bvj = bv[j];
    qv[0] = bqj; qv[1] = bqj; qv[2] = bqj;
    kv[0] = bkj; kv[1] = bkj; kv[2] = bkj;
    vv[0] = bvj; vv[1] = bvj; vv[2] = bvj;
    const float* wqr = Wq + j * 32;
    const float* wkr = Wk + j * 32;
    const float* wvr = Wv + j * 32;
#pragma unroll 8
    for (int k = 0; k < 32; ++k) {
      const float zz0 = shA[slot][0][k], zz1 = shA[slot][1][k],
                  zz2 = shA[slot][2][k];
      const float wq = wqr[k], wk_ = wkr[k], wv_ = wvr[k];
      qv[0] += wq * zz0;  qv[1] += wq * zz1;  qv[2] += wq * zz2;
      kv[0] += wk_ * zz0; kv[1] += wk_ * zz1; kv[2] += wk_ * zz2;
      vv[0] += wv_ * zz0; vv[1] += wv_ * zz1; vv[2] += wv_ * zz2;
    }
  }

  float at[3][3];
#pragma unroll
  for (int s = 0; s < 3; ++s)
#pragma unroll
    for (int t2 = 0; t2 < 3; ++t2) {
      float p = qv[s] * kv[t2];
      p += __shfl_xor(p, 1); p += __shfl_xor(p, 2); p += __shfl_xor(p, 4);
      at[s][t2] = p;
    }
#pragma unroll
  for (int s = 0; s < 3; ++s) {
    const float m = fmaxf(fmaxf(at[s][0], at[s][1]), at[s][2]);
    const float e0 = __expf(at[s][0] - m), e1 = __expf(at[s][1] - m),
                e2 = __expf(at[s][2] - m);
    const float sc = 0.35355339059327373f * __fdividef(1.0f, e0 + e1 + e2);
    at[s][0] = e0 * sc; at[s][1] = e1 * sc; at[s][2] = e2 * sc;
  }
  float zc[3];
#pragma unroll
  for (int s = 0; s < 3; ++s)
    zc[s] = at[s][0] * vv[0] + at[s][1] * vv[1] + at[s][2] * vv[2];
  shB[slot][0][j] = zc[0]; shB[slot][1][j] = zc[1]; shB[slot][2][j] = zc[2];
  __syncthreads();

  const float bzj = bz[j];
  float z2a[3] = {bzj + x0, bzj + x1, bzj + x2};
  {
    const float* wzr = Wz + j * 32;
#pragma unroll 8
    for (int k = 0; k < 32; ++k) {
      const float w = wzr[k];
      z2a[0] += w * shB[slot][0][k];
      z2a[1] += w * shB[slot][1][k];
      z2a[2] += w * shB[slot][2][k];
    }
  }

  float zn[3];
  ln3(z2a[0], z2a[1], z2a[2], g2, be2, zn);
  shA[slot][0][j] = zn[0]; shA[slot][1][j] = zn[1]; shA[slot][2][j] = zn[2];
  __syncthreads();

  const float bffj = bff[j];
  float Za[3] = {bffj + z2a[0], bffj + z2a[1], bffj + z2a[2]};
  {
    const float* wfr = Wff + j * 32;
#pragma unroll 8
    for (int k = 0; k < 32; ++k) {
      const float w = wfr[k];
      Za[0] += w * shA[slot][0][k];
      Za[1] += w * shA[slot][1][k];
      Za[2] += w * shA[slot][2][k];
    }
  }
  shB[slot][0][j] = Za[0]; shB[slot][1][j] = Za[1]; shB[slot][2][j] = Za[2];
  __syncthreads();

  float p = bp1[j];
  {
    const float* wpr = Wp1 + j * 96;
#pragma unroll
    for (int s = 0; s < 3; ++s)
#pragma unroll 8
      for (int k = 0; k < 32; ++k) p += wpr[s * 32 + k] * shB[slot][s][k];
  }
  p = fmaxf(p, 0.0f);
  float l0 = Wp2[j] * p, l1 = Wp2[32 + j] * p;
  l0 += __shfl_xor(l0, 1); l0 += __shfl_xor(l0, 2); l0 += __shfl_xor(l0, 4);
  l0 += __shfl_xor(l0, 8); l0 += __shfl_xor(l0, 16);
  l1 += __shfl_xor(l1, 1); l1 += __shfl_xor(l1, 2); l1 += __shfl_xor(l1, 4);
  l1 += __shfl_xor(l1, 8); l1 += __shfl_xor(l1, 16);
  l0 += bp2[0]; l1 += bp2[1];
  const float mx = fmaxf(l0, l1);
  const float e0 = __expf(l0 - mx), e1 = __expf(l1 - mx);
  const float inv = __fdividef(1.0f, e0 + e1);
  if (j == 0) {
    out[(size_t)n * 2 + 0] = e0 * inv;
    out[(size_t)n * 2 + 1] = e1 * inv;
  }
}

// ---------------------------------------------------------------------------
extern "C" void kernel_launch(void* const* d_in, const int* in_sizes, int n_in,
                              void* d_out, int out_size, void* d_ws,
                              size_t ws_size, hipStream_t stream) {
  const float* l    = (const float*)d_in[0];
  const float* a    = (const float*)d_in[1];
  const float* v    = (const float*)d_in[2];
  const float* lW1  = (const float*)d_in[3];
  const float* lb1  = (const float*)d_in[4];
  const float* lW2  = (const float*)d_in[5];
  const float* lb2  = (const float*)d_in[6];
  const float* aWih = (const float*)d_in[7];
  const float* aWhh = (const float*)d_in[8];
  const float* abih = (const float*)d_in[9];
  const float* abhh = (const float*)d_in[10];
  const float* aWo  = (const float*)d_in[11];
  const float* abo  = (const float*)d_in[12];
  const float* vWih = (const float*)d_in[13];
  const float* vWhh = (const float*)d_in[14];
  const float* vbih = (const float*)d_in[15];
  const float* vbhh = (const float*)d_in[16];
  const float* vWo  = (const float*)d_in[17];
  const float* vbo  = (const float*)d_in[18];
  const float* Wq   = (const float*)d_in[19];
  const float* bq   = (const float*)d_in[20];
  const float* Wk   = (const float*)d_in[21];
  const float* bk   = (const float*)d_in[22];
  const float* Wv   = (const float*)d_in[23];
  const float* bv   = (const float*)d_in[24];
  const float* Wz   = (const float*)d_in[25];
  const float* bz   = (const float*)d_in[26];
  const float* Wff  = (const float*)d_in[27];
  const float* bff  = (const float*)d_in[28];
  const float* g1   = (const float*)d_in[29];
  const float* be1  = (const float*)d_in[30];
  const float* g2   = (const float*)d_in[31];
  const float* be2  = (const float*)d_in[32];
  const float* Wp1  = (const float*)d_in[33];
  const float* bp1  = (const float*)d_in[34];
  const float* Wp2  = (const float*)d_in[35];
  const float* bp2  = (const float*)d_in[36];

  float* out = (float*)d_out;
  float* ws = (float*)d_ws;
  float* lfw = ws;
  float* afw = ws + 4096 * 32;
  float* vfw = ws + 2 * 4096 * 32;

  hipLaunchKernelGGL(lstm_both, dim3(512), dim3(256), 0, stream, a, v, aWih,
                     aWhh, abih, abhh, aWo, abo, vWih, vWhh, vbih, vbhh, vWo,
                     vbo, l, lW1, lb1, lW2, lb2, lfw, afw, vfw);
  hipLaunchKernelGGL(head_kernel, dim3(512), dim3(256), 0, stream, lfw, afw,
                     vfw, Wq, bq, Wk, bk, Wv, bv, Wz, bz, Wff, bff, g1, be1,
                     g2, be2, Wp1, bp1, Wp2, bp2, out);
}